// Round 6
// baseline (68741.730 us; speedup 1.0000x reference)
//
#include <hip/hip_runtime.h>
#include <hip/hip_bf16.h>
#include <cstdint>
#include <cstddef>

using bf16 = __hip_bfloat16;

static constexpr int DD = 31;                      // depth (time) extent
static constexpr long long U  = 31LL * 256 * 256;  // 2,031,616 elems (1 ch @256)
static constexpr long long V2 = 31LL * 128 * 128;  //   507,904 (1 ch @128)
static constexpr long long V3 = 31LL * 64 * 64;    //   126,976 (1 ch @64)
static constexpr long long POOL_UNITS = 56;        // pool = 56*U elems

__device__ __forceinline__ float toF(float v) { return v; }
__device__ __forceinline__ float toF(bf16 v) { return __bfloat162float(v); }
__device__ __forceinline__ void stv(float* p, float v) { *p = v; }
__device__ __forceinline__ void stv(bf16* p, float v) { *p = __float2bfloat16(v); }
__device__ __forceinline__ float sigm(float x) { return 1.f / (1.f + __expf(-x)); }

// ---------------------------------------------------------------------------
template<typename T>
__global__ __launch_bounds__(256)
void fill_k(T* p, long long n)
{
    const long long stride = (long long)gridDim.x * 256;
    for (long long i = (long long)blockIdx.x * 256 + threadIdx.x; i < n; i += stride)
        stv(p + i, 0.f);
}

// ---------------------------------------------------------------------------
// Direct 3D conv, kernel 3x3x3, pad 1. Each thread computes 4 consecutive-w
// outputs of one output channel (blockIdx.y relative to chunk). Weights (fp32)
// staged in LDS. FLIP=true -> deconv3d (flip d,h,w).
// Requires DD*Hout*Wout % 1024 == 0, Wout % 4 == 0. STRIDE==1 -> Win==Wout.
// ---------------------------------------------------------------------------
template<typename TIN, typename T, int STRIDE, bool FLIP>
__global__ __launch_bounds__(256)
void conv3d_k(const TIN* __restrict__ in, const float* __restrict__ wt,
              const float* __restrict__ bias, T* __restrict__ out,
              int Cin, int Hin, int Win, int Hout, int Wout)
{
    extern __shared__ float wl[];
    const int co = blockIdx.y;
    const int nw = Cin * 27;
    for (int t = threadIdx.x; t < nw; t += 256) {
        int src;
        if (FLIP) {
            const int ci = t / 27, r = t % 27;
            const int kd = r / 9, kh = (r / 3) % 3, kw = r % 3;
            src = ci * 27 + (2 - kd) * 9 + (2 - kh) * 3 + (2 - kw);
        } else {
            src = t;
        }
        wl[t] = wt[(size_t)co * nw + src];
    }
    __syncthreads();

    const int s4 = (blockIdx.x * 256 + threadIdx.x) * 4;
    const int w0 = s4 % Wout;
    const int sh = s4 / Wout;
    const int h0 = sh % Hout;
    const int d0 = sh / Hout;

    const float bv = bias[co];
    float a0 = bv, a1 = bv, a2 = bv, a3 = bv;
    const size_t HWin = (size_t)Hin * Win;
    constexpr int WL = 3 * STRIDE + 3;  // input window width covering 4 outputs

    for (int ci = 0; ci < Cin; ++ci) {
        const TIN* cb = in + (size_t)ci * DD * HWin;
        const float* wc = wl + ci * 27;
#pragma unroll
        for (int kd = 0; kd < 3; ++kd) {
            const int di = d0 + kd - 1;
            if (di < 0 || di >= DD) continue;
#pragma unroll
            for (int kh = 0; kh < 3; ++kh) {
                const int hi = h0 * STRIDE + kh - 1;
                if (hi < 0 || hi >= Hin) continue;
                const TIN* row = cb + (size_t)di * HWin + (size_t)hi * Win
                                 + (size_t)w0 * STRIDE;
                float v[WL];
                v[0] = (w0 > 0) ? toF(row[-1]) : 0.f;
#pragma unroll
                for (int t = 1; t < WL - 1; ++t) v[t] = toF(row[t - 1]);
                if (STRIDE == 1) {
                    v[WL - 1] = (w0 + 4 < Win) ? toF(row[WL - 2]) : 0.f;
                } else {
                    v[WL - 1] = toF(row[WL - 2]);  // 2*w0+7 <= Win-1 always
                }
                const float* wk = wc + kd * 9 + kh * 3;
#pragma unroll
                for (int kw = 0; kw < 3; ++kw) {
                    const float wv = wk[kw];
                    a0 = fmaf(v[0 * STRIDE + kw], wv, a0);
                    a1 = fmaf(v[1 * STRIDE + kw], wv, a1);
                    a2 = fmaf(v[2 * STRIDE + kw], wv, a2);
                    a3 = fmaf(v[3 * STRIDE + kw], wv, a3);
                }
            }
        }
    }
    T* op = out + (((size_t)co * DD + d0) * Hout + h0) * Wout + w0;
    stv(op + 0, a0); stv(op + 1, a1); stv(op + 2, a2); stv(op + 3, a3);
}

// ---------------------------------------------------------------------------
// Fused: conv3d( upsample2x(a + b) ), stride 1, no flip. a,b half-res
// [Cin, DD, Hlo, Wlo]; output full-res [nCo, DD, 2*Hlo, 2*Wlo].
// ---------------------------------------------------------------------------
template<typename T>
__global__ __launch_bounds__(256)
void conv3d_up_k(const T* __restrict__ ia, const T* __restrict__ ib,
                 const float* __restrict__ wt, const float* __restrict__ bias,
                 T* __restrict__ out, int Cin, int Hlo, int Wlo)
{
    extern __shared__ float wl[];
    const int co = blockIdx.y;
    const int nw = Cin * 27;
    for (int t = threadIdx.x; t < nw; t += 256)
        wl[t] = wt[(size_t)co * nw + t];
    __syncthreads();

    const int Hout = 2 * Hlo, Wout = 2 * Wlo;
    const int s4 = (blockIdx.x * 256 + threadIdx.x) * 4;
    const int w0 = s4 % Wout;                  // multiple of 4
    const int sh = s4 / Wout;
    const int h0 = sh % Hout;
    const int d0 = sh / Hout;
    const int lw = w0 >> 1;

    const float bv = bias[co];
    float a0 = bv, a1 = bv, a2 = bv, a3 = bv;
    const size_t HWlo = (size_t)Hlo * Wlo;

    for (int ci = 0; ci < Cin; ++ci) {
        const T* cba = ia + (size_t)ci * DD * HWlo;
        const T* cbb = ib + (size_t)ci * DD * HWlo;
        const float* wc = wl + ci * 27;
#pragma unroll
        for (int kd = 0; kd < 3; ++kd) {
            const int di = d0 + kd - 1;
            if (di < 0 || di >= DD) continue;
#pragma unroll
            for (int kh = 0; kh < 3; ++kh) {
                const int hi = h0 + kh - 1;
                if (hi < 0 || hi >= Hout) continue;
                const int hlo = hi >> 1;
                const T* ra = cba + (size_t)di * HWlo + (size_t)hlo * Wlo;
                const T* rb = cbb + (size_t)di * HWlo + (size_t)hlo * Wlo;
                float u[4];
#pragma unroll
                for (int j = 0; j < 4; ++j) {
                    const int lj = lw - 1 + j;
                    u[j] = (lj >= 0 && lj < Wlo) ? (toF(ra[lj]) + toF(rb[lj])) : 0.f;
                }
                const float v0 = u[0], v1 = u[1], v2 = u[1], v3 = u[2],
                            v4 = u[2], v5 = u[3];
                const float* wk = wc + kd * 9 + kh * 3;
                const float q0 = wk[0], q1 = wk[1], q2 = wk[2];
                a0 = fmaf(v0, q0, fmaf(v1, q1, fmaf(v2, q2, a0)));
                a1 = fmaf(v1, q0, fmaf(v2, q1, fmaf(v3, q2, a1)));
                a2 = fmaf(v2, q0, fmaf(v3, q1, fmaf(v4, q2, a2)));
                a3 = fmaf(v3, q0, fmaf(v4, q1, fmaf(v5, q2, a3)));
            }
        }
    }
    T* op = out + (((size_t)co * DD + d0) * Hout + h0) * Wout + w0;
    stv(op + 0, a0); stv(op + 1, a1); stv(op + 2, a2); stv(op + 3, a3);
}

// ---------------------------------------------------------------------------
// fo_pool over D=31. z/f are per-channel [C, D, HW] bases (explicit ptrs).
// out[off] = h_d + a1[off]? + a2[off]?   (a1/a2 nullable). No aliasing used.
// ---------------------------------------------------------------------------
template<typename T, typename TA2, typename TO>
__global__ __launch_bounds__(256)
void fo_pool_k(const T* __restrict__ z, const T* __restrict__ f,
               TO* __restrict__ out, const T* __restrict__ a1,
               const TA2* __restrict__ a2, int C, int HW, int reverse)
{
    const long long idx = (long long)blockIdx.x * 256 + threadIdx.x;
    const int c = (int)(idx / HW);
    if (c >= C) return;
    const int p = (int)(idx - (long long)c * HW);
    const size_t base = (size_t)c * DD * HW + p;
    float h = 0.f;
    if (!reverse) {
        for (int d = 0; d < DD; ++d) {
            const size_t off = base + (size_t)d * HW;
            const float zz = tanhf(toF(z[off]));
            const float ff = sigm(toF(f[off]));
            h = ff * h + (1.f - ff) * zz;
            float v = h;
            if (a1) v += toF(a1[off]);
            if (a2) v += toF(a2[off]);
            stv(out + off, v);
        }
    } else {
        for (int d = DD - 1; d >= 0; --d) {
            const size_t off = base + (size_t)d * HW;
            const float zz = tanhf(toF(z[off]));
            const float ff = sigm(toF(f[off]));
            h = ff * h + (1.f - ff) * zz;
            float v = h;
            if (a1) v += toF(a1[off]);
            if (a2) v += toF(a2[off]);
            stv(out + off, v);
        }
    }
}

// Diagnostic: encode ws_size (MB) into output if workspace too small.
__global__ __launch_bounds__(256)
void diag_k(float* out, float v, int n)
{
    const int i = blockIdx.x * 256 + threadIdx.x;
    if (i < n) out[i] = v;
}

// ---------------------------------------------------------------------------

template<typename TIN, typename T>
static inline void conv_launch(const TIN* in, const float* w, const float* b,
                               T* out, int Cin, int co0, int nCo,
                               int Hin, int Win, int Hout, int Wout,
                               int stride, bool flip, hipStream_t s)
{
    dim3 grid((unsigned)((DD * (long long)Hout * Wout) / 1024), nCo);
    const size_t shm = (size_t)Cin * 27 * sizeof(float);
    const float* wp = w + (size_t)co0 * Cin * 27;
    const float* bp = b + co0;
    if (stride == 2)
        conv3d_k<TIN, T, 2, false><<<grid, 256, shm, s>>>(in, wp, bp, out, Cin, Hin, Win, Hout, Wout);
    else if (flip)
        conv3d_k<TIN, T, 1, true><<<grid, 256, shm, s>>>(in, wp, bp, out, Cin, Hin, Win, Hout, Wout);
    else
        conv3d_k<TIN, T, 1, false><<<grid, 256, shm, s>>>(in, wp, bp, out, Cin, Hin, Win, Hout, Wout);
}

template<typename T>
static inline void conv_up_launch(const T* ia, const T* ib, const float* w,
                                  const float* b, T* out, int Cin, int co0,
                                  int nCo, int Hlo, int Wlo, hipStream_t s)
{
    dim3 grid((unsigned)((DD * 4LL * Hlo * Wlo) / 1024), nCo);
    const size_t shm = (size_t)Cin * 27 * sizeof(float);
    conv3d_up_k<T><<<grid, 256, shm, s>>>(ia, ib, w + (size_t)co0 * Cin * 27,
                                          b + co0, out, Cin, Hlo, Wlo);
}

template<typename T, typename TA2, typename TO>
static inline void pool_launch(const T* z, const T* f, TO* o, const T* a1,
                               const TA2* a2, int C, int HW, int rev,
                               hipStream_t s)
{
    const long long tot = (long long)C * HW;
    fo_pool_k<T, TA2, TO><<<(unsigned)((tot + 255) / 256), 256, 0, s>>>(
        z, f, o, a1, a2, C, HW, rev);
}

// ---------------------------------------------------------------------------
// Memory plan (units of U = one @256 channel). Pool = 56 U. No kernel ever
// has out aliasing one of its inputs; slots reused only after last read.
//   fe:   FE=[32,48)  gates z[0,4) f1[4,8) f2[8,12) tmp[12,16)
//   e0:   E0=[16,32)  gates z[0,8) f[8,16)
//   e1:   E1=[0,8)    gates [32,48)   (64ch @V2)
//   e2:   E2=[8,16)   gates [32,48)
//   e3:   E3=[32,36)  gates [48,56)   (128ch @V3)
//   e4:   E4=[40,44)  gates [48,56)
//   d0:   D0=[44,48)  gates [48,56)
//   d1:   D1=[36,44)  gates z[48,50) f[50,52)  res E2
//   d2:   D2=[8,16)   gates z[48,52) f[52,56)
//   d3:   D3=[32,48)  gates z[48,52) f[52,56)  res E0
//   FE2:  FE2=[0,16)  gates z[16,20) f1[20,24) f2[24,28) tmp[28,32)
//   d4:   D4=[16,32)  gates z[48,52) f[52,56)  res FE2
//   rec:  gates [32,35) tmp [35,36); out=d_out (fp32), adds tmp + x
// ---------------------------------------------------------------------------
template<typename T>
static void run_net(const float* x, const float* const* W, const float* const* B,
                    float* out, T* P, hipStream_t s)
{
    const T* np = nullptr;
    const T* np2 = nullptr;

    fill_k<T><<<2048, 256, 0, s>>>(P, POOL_UNITS * U);

    T* FE = P + 32 * U;
    // ---- fe = biqrnn(conv(x)) : 1 -> 48 gates -> 16 ch @256, chunks of 4 ---
    for (int a = 0; a < 16; a += 4) {
        conv_launch<float, T>(x, W[0], B[0], P,         1, a,      4, 256, 256, 256, 256, 1, false, s);
        conv_launch<float, T>(x, W[0], B[0], P + 4 * U, 1, 16 + a, 4, 256, 256, 256, 256, 1, false, s);
        conv_launch<float, T>(x, W[0], B[0], P + 8 * U, 1, 32 + a, 4, 256, 256, 256, 256, 1, false, s);
        pool_launch<T, T, T>(P, P + 4 * U, P + 12 * U, np, np2, 4, 65536, 0, s);
        pool_launch<T, T, T>(P, P + 8 * U, FE + (size_t)a * U, P + 12 * U, np2, 4, 65536, 1, s);
    }

    // ---- e0 = qrnn(conv(fe), fwd) : 16 -> 32 -> 16 @256, chunks of 8 -------
    T* E0 = P + 16 * U;
    for (int a = 0; a < 16; a += 8) {
        conv_launch<T, T>(FE, W[1], B[1], P,         16, a,      8, 256, 256, 256, 256, 1, false, s);
        conv_launch<T, T>(FE, W[1], B[1], P + 8 * U, 16, 16 + a, 8, 256, 256, 256, 256, 1, false, s);
        pool_launch<T, T, T>(P, P + 8 * U, E0 + (size_t)a * U, np, np2, 8, 65536, 0, s);
    }
    // FE dead (recomputed later).

    // ---- e1 = qrnn(conv(e0, s2), rev) : 16 -> 64 -> 32 @128 ----------------
    T* E1 = P;
    {
        T* G = P + 32 * U;
        conv_launch<T, T>(E0, W[2], B[2], G, 16, 0, 64, 256, 256, 128, 128, 2, false, s);
        pool_launch<T, T, T>(G, G + 8 * U, E1, np, np2, 32, 16384, 1, s);
    }

    // ---- e2 = qrnn(conv(e1), fwd) : 32 -> 64 -> 32 @128 --------------------
    T* E2 = P + 8 * U;
    {
        T* G = P + 32 * U;
        conv_launch<T, T>(E1, W[3], B[3], G, 32, 0, 64, 128, 128, 128, 128, 1, false, s);
        pool_launch<T, T, T>(G, G + 8 * U, E2, np, np2, 32, 16384, 0, s);
    }

    // ---- e3 = qrnn(conv(e2, s2), rev) : 32 -> 128 -> 64 @64 ----------------
    T* E3 = P + 32 * U;
    {
        T* G = P + 48 * U;
        conv_launch<T, T>(E2, W[4], B[4], G, 32, 0, 128, 128, 128, 64, 64, 2, false, s);
        pool_launch<T, T, T>(G, G + 4 * U, E3, np, np2, 64, 4096, 1, s);
    }

    // ---- e4 = qrnn(conv(e3), fwd) : 64 -> 128 -> 64 @64 --------------------
    T* E4 = P + 40 * U;
    {
        T* G = P + 48 * U;
        conv_launch<T, T>(E3, W[5], B[5], G, 64, 0, 128, 64, 64, 64, 64, 1, false, s);
        pool_launch<T, T, T>(G, G + 4 * U, E4, np, np2, 64, 4096, 0, s);
    }

    // ---- d0 = qrnn(deconv(e4), rev) : 64 -> 128 -> 64 @64 ------------------
    T* D0 = P + 44 * U;
    {
        T* G = P + 48 * U;
        conv_launch<T, T>(E4, W[6], B[6], G, 64, 0, 128, 64, 64, 64, 64, 1, true, s);
        pool_launch<T, T, T>(G, G + 4 * U, D0, np, np2, 64, 4096, 1, s);
    }
    // E4 dead.

    // ---- d1 = qrnn(conv(up(d0+e3)), fwd) + e2 : 64 -> 64 -> 32 @128 --------
    T* D1 = P + 36 * U;
    for (int a = 0; a < 32; a += 8) {
        T* G = P + 48 * U;  // z 8ch@V2=2U, f 2U
        conv_up_launch<T>(D0, E3, W[7], B[7], G,         64, a,      8, 64, 64, s);
        conv_up_launch<T>(D0, E3, W[7], B[7], G + 2 * U, 64, 32 + a, 8, 64, 64, s);
        pool_launch<T, T, T>(G, G + 2 * U, D1 + (size_t)a * V2,
                             E2 + (size_t)a * V2, np2, 8, 16384, 0, s);
    }
    // E2, E3, D0 dead.

    // ---- d2 = qrnn(deconv(d1), rev) : 32 -> 64 -> 32 @128 ------------------
    T* D2 = P + 8 * U;  // over dead E2
    for (int a = 0; a < 32; a += 16) {
        T* G = P + 48 * U;  // z 16ch@V2=4U, f 4U
        conv_launch<T, T>(D1, W[8], B[8], G,         32, a,      16, 128, 128, 128, 128, 1, true, s);
        conv_launch<T, T>(D1, W[8], B[8], G + 4 * U, 32, 32 + a, 16, 128, 128, 128, 128, 1, true, s);
        pool_launch<T, T, T>(G, G + 4 * U, D2 + (size_t)a * V2, np, np2, 16, 16384, 1, s);
    }
    // D1 dead.

    // ---- d3 = qrnn(conv(up(d2+e1)), fwd) + e0 : 32 -> 32 -> 16 @256 --------
    T* D3 = P + 32 * U;  // fresh 16U
    for (int a = 0; a < 16; a += 4) {
        T* G = P + 48 * U;  // z 4ch@U=4U, f 4U
        conv_up_launch<T>(D2, E1, W[9], B[9], G,         32, a,      4, 128, 128, s);
        conv_up_launch<T>(D2, E1, W[9], B[9], G + 4 * U, 32, 16 + a, 4, 128, 128, s);
        pool_launch<T, T, T>(G, G + 4 * U, D3 + (size_t)a * U,
                             E0 + (size_t)a * U, np2, 4, 65536, 0, s);
    }
    // E0, E1, D2 dead.

    // ---- recompute fe -> FE2 = [0,16), gates at [16,32) --------------------
    T* FE2 = P;
    for (int a = 0; a < 16; a += 4) {
        T* G = P + 16 * U;
        conv_launch<float, T>(x, W[0], B[0], G,         1, a,      4, 256, 256, 256, 256, 1, false, s);
        conv_launch<float, T>(x, W[0], B[0], G + 4 * U, 1, 16 + a, 4, 256, 256, 256, 256, 1, false, s);
        conv_launch<float, T>(x, W[0], B[0], G + 8 * U, 1, 32 + a, 4, 256, 256, 256, 256, 1, false, s);
        pool_launch<T, T, T>(G, G + 4 * U, G + 12 * U, np, np2, 4, 65536, 0, s);
        pool_launch<T, T, T>(G, G + 8 * U, FE2 + (size_t)a * U, G + 12 * U, np2, 4, 65536, 1, s);
    }

    // ---- d4 = qrnn(deconv(d3), rev) + fe : 16 -> 32 -> 16 @256 -------------
    T* D4 = P + 16 * U;  // fresh (over dead FE2-gates region)
    for (int a = 0; a < 16; a += 4) {
        T* G = P + 48 * U;
        conv_launch<T, T>(D3, W[10], B[10], G,         16, a,      4, 256, 256, 256, 256, 1, true, s);
        conv_launch<T, T>(D3, W[10], B[10], G + 4 * U, 16, 16 + a, 4, 256, 256, 256, 256, 1, true, s);
        pool_launch<T, T, T>(G, G + 4 * U, D4 + (size_t)a * U,
                             FE2 + (size_t)a * U, np2, 4, 65536, 1, s);
    }
    // D3, FE2 dead.

    // ---- out = biqrnn(deconv(d4)) + x : 16 -> 3 -> 1 @256 -> fp32 d_out ----
    {
        T* G = P + 32 * U;     // ch0 z, ch1 f1, ch2 f2
        T* TMP = P + 35 * U;
        conv_launch<T, T>(D4, W[11], B[11], G, 16, 0, 3, 256, 256, 256, 256, 1, true, s);
        pool_launch<T, T, T>(G, G + 1 * U, TMP, np, np2, 1, 65536, 0, s);
        pool_launch<T, float, float>(G, G + 2 * U, out, TMP, x, 1, 65536, 1, s);
    }
}

extern "C" void kernel_launch(void* const* d_in, const int* in_sizes, int n_in,
                              void* d_out, int out_size, void* d_ws, size_t ws_size,
                              hipStream_t stream)
{
    const float* x = (const float*)d_in[0];
    const float* W[12];
    const float* B[12];
    for (int i = 0; i < 12; ++i) {
        W[i] = (const float*)d_in[1 + 2 * i];
        B[i] = (const float*)d_in[2 + 2 * i];
    }

    const size_t need_f32 = (size_t)(POOL_UNITS * U) * sizeof(float);  // ~455 MB
    const size_t need_b16 = (size_t)(POOL_UNITS * U) * sizeof(bf16);   // ~227 MB
    if (ws_size >= need_f32) {
        run_net<float>(x, W, B, (float*)d_out, (float*)d_ws, stream);
    } else if (ws_size >= need_b16) {
        run_net<bf16>(x, W, B, (float*)d_out, (bf16*)d_ws, stream);
    } else {
        const float ws_mb = (float)((double)ws_size / 1048576.0);
        diag_k<<<(out_size + 255) / 256, 256, 0, stream>>>(
            (float*)d_out, ws_mb, out_size);
    }
}

// Round 7
// 24727.441 us; speedup vs baseline: 2.7800x; 2.7800x over previous
//
#include <hip/hip_runtime.h>
#include <hip/hip_bf16.h>
#include <cstdint>
#include <cstddef>

using bf16 = __hip_bfloat16;

static constexpr int DD = 31;                      // depth (time) extent
static constexpr long long U  = 31LL * 256 * 256;  // 2,031,616 elems (1 ch @256)
static constexpr long long V2 = 31LL * 128 * 128;  //   507,904 (1 ch @128)
static constexpr long long V3 = 31LL * 64 * 64;    //   126,976 (1 ch @64)
static constexpr long long POOL_UNITS = 56;        // pool = 56*U elems

__device__ __forceinline__ float toF(float v) { return v; }
__device__ __forceinline__ float toF(bf16 v) { return __bfloat162float(v); }
__device__ __forceinline__ void stv(float* p, float v) { *p = v; }
__device__ __forceinline__ void stv(bf16* p, float v) { *p = __float2bfloat16(v); }
__device__ __forceinline__ float sigm(float x) { return 1.f / (1.f + __expf(-x)); }

// ---------------------------------------------------------------------------
template<typename T>
__global__ __launch_bounds__(256)
void fill_k(T* p, long long n)
{
    const long long stride = (long long)gridDim.x * 256;
    for (long long i = (long long)blockIdx.x * 256 + threadIdx.x; i < n; i += stride)
        stv(p + i, 0.f);
}

// ---------------------------------------------------------------------------
// Direct 3D conv, kernel 3x3x3, pad 1, CO_BLK output channels per block.
// Each thread computes 4 consecutive-w outputs for CO_BLK channels: the 6
// input-window loads per (ci,kd,kh) feed 12*CO_BLK FMAs (latency hiding).
// Weights staged in LDS transposed to [ci*27+k][CO_BLK] so the inner loop
// reads CO_BLK-contiguous floats (merged ds_read). FLIP applied at staging.
// Requires DD*Hout*Wout % 1024 == 0, Wout % 4 == 0. STRIDE==1 -> Win==Wout.
// ---------------------------------------------------------------------------
template<typename TIN, typename T, int STRIDE, bool FLIP, int CO_BLK>
__global__ __launch_bounds__(256)
void conv3d_k(const TIN* __restrict__ in, const float* __restrict__ wt,
              const float* __restrict__ bias, T* __restrict__ out,
              int Cin, int Hin, int Win, int Hout, int Wout)
{
    extern __shared__ float wl[];  // [Cin*27][CO_BLK]
    const int co_base = blockIdx.y * CO_BLK;
    const int nw = Cin * 27;
    for (int t = threadIdx.x; t < nw * CO_BLK; t += 256) {
        const int j = t % CO_BLK;
        const int klin = t / CO_BLK;
        const int ci = klin / 27;
        const int r = klin % 27;
        int src;
        if (FLIP) {
            const int kd = r / 9, kh = (r / 3) % 3, kw = r % 3;
            src = (2 - kd) * 9 + (2 - kh) * 3 + (2 - kw);
        } else {
            src = r;
        }
        wl[t] = wt[((size_t)(co_base + j) * Cin + ci) * 27 + src];
    }
    __syncthreads();

    const int s4 = (blockIdx.x * 256 + threadIdx.x) * 4;
    const int w0 = s4 % Wout;
    const int sh = s4 / Wout;
    const int h0 = sh % Hout;
    const int d0 = sh / Hout;

    float acc[CO_BLK][4];
#pragma unroll
    for (int j = 0; j < CO_BLK; ++j) {
        const float bv = bias[co_base + j];
        acc[j][0] = bv; acc[j][1] = bv; acc[j][2] = bv; acc[j][3] = bv;
    }

    const size_t HWin = (size_t)Hin * Win;
    constexpr int WL = 3 * STRIDE + 3;  // input window covering 4 outputs

    for (int ci = 0; ci < Cin; ++ci) {
        const TIN* cb = in + (size_t)ci * DD * HWin;
        const float* wc = wl + ci * 27 * CO_BLK;
#pragma unroll
        for (int kd = 0; kd < 3; ++kd) {
            const int di = d0 + kd - 1;
            if (di < 0 || di >= DD) continue;
#pragma unroll
            for (int kh = 0; kh < 3; ++kh) {
                const int hi = h0 * STRIDE + kh - 1;
                if (hi < 0 || hi >= Hin) continue;
                const TIN* row = cb + (size_t)di * HWin + (size_t)hi * Win
                                 + (size_t)w0 * STRIDE;
                float v[WL];
                v[0] = (w0 > 0) ? toF(row[-1]) : 0.f;
#pragma unroll
                for (int t = 1; t < WL - 1; ++t) v[t] = toF(row[t - 1]);
                if (STRIDE == 1) {
                    v[WL - 1] = (w0 + 4 < Win) ? toF(row[WL - 2]) : 0.f;
                } else {
                    v[WL - 1] = toF(row[WL - 2]);  // 2*w0+7 <= Win-1 always
                }
                const float* wk = wc + (kd * 9 + kh * 3) * CO_BLK;
#pragma unroll
                for (int kw = 0; kw < 3; ++kw) {
#pragma unroll
                    for (int j = 0; j < CO_BLK; ++j) {
                        const float wv = wk[kw * CO_BLK + j];
                        acc[j][0] = fmaf(v[0 * STRIDE + kw], wv, acc[j][0]);
                        acc[j][1] = fmaf(v[1 * STRIDE + kw], wv, acc[j][1]);
                        acc[j][2] = fmaf(v[2 * STRIDE + kw], wv, acc[j][2]);
                        acc[j][3] = fmaf(v[3 * STRIDE + kw], wv, acc[j][3]);
                    }
                }
            }
        }
    }
#pragma unroll
    for (int j = 0; j < CO_BLK; ++j) {
        T* op = out + (((size_t)(co_base + j) * DD + d0) * Hout + h0) * Wout + w0;
        stv(op + 0, acc[j][0]); stv(op + 1, acc[j][1]);
        stv(op + 2, acc[j][2]); stv(op + 3, acc[j][3]);
    }
}

// ---------------------------------------------------------------------------
// Fused: conv3d( upsample2x(a + b) ), stride 1, no flip, CO_BLK channels per
// block. a,b half-res [Cin, DD, Hlo, Wlo]; out [nCo, DD, 2*Hlo, 2*Wlo].
// ---------------------------------------------------------------------------
template<typename T, int CO_BLK>
__global__ __launch_bounds__(256)
void conv3d_up_k(const T* __restrict__ ia, const T* __restrict__ ib,
                 const float* __restrict__ wt, const float* __restrict__ bias,
                 T* __restrict__ out, int Cin, int Hlo, int Wlo)
{
    extern __shared__ float wl[];  // [Cin*27][CO_BLK]
    const int co_base = blockIdx.y * CO_BLK;
    const int nw = Cin * 27;
    for (int t = threadIdx.x; t < nw * CO_BLK; t += 256) {
        const int j = t % CO_BLK;
        const int klin = t / CO_BLK;
        wl[t] = wt[((size_t)(co_base + j) * Cin) * 27 + klin];
    }
    __syncthreads();

    const int Hout = 2 * Hlo, Wout = 2 * Wlo;
    const int s4 = (blockIdx.x * 256 + threadIdx.x) * 4;
    const int w0 = s4 % Wout;                  // multiple of 4
    const int sh = s4 / Wout;
    const int h0 = sh % Hout;
    const int d0 = sh / Hout;
    const int lw = w0 >> 1;

    float acc[CO_BLK][4];
#pragma unroll
    for (int j = 0; j < CO_BLK; ++j) {
        const float bv = bias[co_base + j];
        acc[j][0] = bv; acc[j][1] = bv; acc[j][2] = bv; acc[j][3] = bv;
    }
    const size_t HWlo = (size_t)Hlo * Wlo;

    for (int ci = 0; ci < Cin; ++ci) {
        const T* cba = ia + (size_t)ci * DD * HWlo;
        const T* cbb = ib + (size_t)ci * DD * HWlo;
        const float* wc = wl + ci * 27 * CO_BLK;
#pragma unroll
        for (int kd = 0; kd < 3; ++kd) {
            const int di = d0 + kd - 1;
            if (di < 0 || di >= DD) continue;
#pragma unroll
            for (int kh = 0; kh < 3; ++kh) {
                const int hi = h0 + kh - 1;
                if (hi < 0 || hi >= Hout) continue;
                const int hlo = hi >> 1;
                const T* ra = cba + (size_t)di * HWlo + (size_t)hlo * Wlo;
                const T* rb = cbb + (size_t)di * HWlo + (size_t)hlo * Wlo;
                float u[4];
#pragma unroll
                for (int jj = 0; jj < 4; ++jj) {
                    const int lj = lw - 1 + jj;
                    u[jj] = (lj >= 0 && lj < Wlo) ? (toF(ra[lj]) + toF(rb[lj])) : 0.f;
                }
                // upsampled window: w0-1 .. w0+4
                const float v0 = u[0], v1 = u[1], v2 = u[1], v3 = u[2],
                            v4 = u[2], v5 = u[3];
                const float* wk = wc + (kd * 9 + kh * 3) * CO_BLK;
#pragma unroll
                for (int j = 0; j < CO_BLK; ++j) {
                    const float q0 = wk[0 * CO_BLK + j];
                    const float q1 = wk[1 * CO_BLK + j];
                    const float q2 = wk[2 * CO_BLK + j];
                    acc[j][0] = fmaf(v0, q0, fmaf(v1, q1, fmaf(v2, q2, acc[j][0])));
                    acc[j][1] = fmaf(v1, q0, fmaf(v2, q1, fmaf(v3, q2, acc[j][1])));
                    acc[j][2] = fmaf(v2, q0, fmaf(v3, q1, fmaf(v4, q2, acc[j][2])));
                    acc[j][3] = fmaf(v3, q0, fmaf(v4, q1, fmaf(v5, q2, acc[j][3])));
                }
            }
        }
    }
#pragma unroll
    for (int j = 0; j < CO_BLK; ++j) {
        T* op = out + (((size_t)(co_base + j) * DD + d0) * Hout + h0) * Wout + w0;
        stv(op + 0, acc[j][0]); stv(op + 1, acc[j][1]);
        stv(op + 2, acc[j][2]); stv(op + 3, acc[j][3]);
    }
}

// ---------------------------------------------------------------------------
// fo_pool over D=31. z/f are per-channel [C, D, HW] bases (explicit ptrs).
// out[off] = h_d + a1[off]? + a2[off]?   (a1/a2 nullable). No aliasing used.
// ---------------------------------------------------------------------------
template<typename T, typename TA2, typename TO>
__global__ __launch_bounds__(256)
void fo_pool_k(const T* __restrict__ z, const T* __restrict__ f,
               TO* __restrict__ out, const T* __restrict__ a1,
               const TA2* __restrict__ a2, int C, int HW, int reverse)
{
    const long long idx = (long long)blockIdx.x * 256 + threadIdx.x;
    const int c = (int)(idx / HW);
    if (c >= C) return;
    const int p = (int)(idx - (long long)c * HW);
    const size_t base = (size_t)c * DD * HW + p;
    float h = 0.f;
    if (!reverse) {
        for (int d = 0; d < DD; ++d) {
            const size_t off = base + (size_t)d * HW;
            const float zz = tanhf(toF(z[off]));
            const float ff = sigm(toF(f[off]));
            h = ff * h + (1.f - ff) * zz;
            float v = h;
            if (a1) v += toF(a1[off]);
            if (a2) v += toF(a2[off]);
            stv(out + off, v);
        }
    } else {
        for (int d = DD - 1; d >= 0; --d) {
            const size_t off = base + (size_t)d * HW;
            const float zz = tanhf(toF(z[off]));
            const float ff = sigm(toF(f[off]));
            h = ff * h + (1.f - ff) * zz;
            float v = h;
            if (a1) v += toF(a1[off]);
            if (a2) v += toF(a2[off]);
            stv(out + off, v);
        }
    }
}

// Diagnostic: encode ws_size (MB) into output if workspace too small.
__global__ __launch_bounds__(256)
void diag_k(float* out, float v, int n)
{
    const int i = blockIdx.x * 256 + threadIdx.x;
    if (i < n) out[i] = v;
}

// ---------------------------------------------------------------------------

template<typename TIN, typename T>
static inline void conv_launch(const TIN* in, const float* w, const float* b,
                               T* out, int Cin, int co0, int nCo,
                               int Hin, int Win, int Hout, int Wout,
                               int stride, bool flip, hipStream_t s)
{
    const unsigned gx = (unsigned)((DD * (long long)Hout * Wout) / 1024);
    const float* wp = w + (size_t)co0 * Cin * 27;
    const float* bp = b + co0;
    if (stride == 2) {
        dim3 grid(gx, nCo / 4);
        conv3d_k<TIN, T, 2, false, 4><<<grid, 256, (size_t)Cin * 27 * 4 * 4, s>>>(
            in, wp, bp, out, Cin, Hin, Win, Hout, Wout);
    } else if (flip) {
        if (nCo % 4 == 0) {
            dim3 grid(gx, nCo / 4);
            conv3d_k<TIN, T, 1, true, 4><<<grid, 256, (size_t)Cin * 27 * 4 * 4, s>>>(
                in, wp, bp, out, Cin, Hin, Win, Hout, Wout);
        } else {  // rec layer: nCo == 3
            dim3 grid(gx, nCo / 3);
            conv3d_k<TIN, T, 1, true, 3><<<grid, 256, (size_t)Cin * 27 * 3 * 4, s>>>(
                in, wp, bp, out, Cin, Hin, Win, Hout, Wout);
        }
    } else {
        dim3 grid(gx, nCo / 4);
        conv3d_k<TIN, T, 1, false, 4><<<grid, 256, (size_t)Cin * 27 * 4 * 4, s>>>(
            in, wp, bp, out, Cin, Hin, Win, Hout, Wout);
    }
}

template<typename T>
static inline void conv_up_launch(const T* ia, const T* ib, const float* w,
                                  const float* b, T* out, int Cin, int co0,
                                  int nCo, int Hlo, int Wlo, hipStream_t s)
{
    dim3 grid((unsigned)((DD * 4LL * Hlo * Wlo) / 1024), nCo / 4);
    conv3d_up_k<T, 4><<<grid, 256, (size_t)Cin * 27 * 4 * 4, s>>>(
        ia, ib, w + (size_t)co0 * Cin * 27, b + co0, out, Cin, Hlo, Wlo);
}

template<typename T, typename TA2, typename TO>
static inline void pool_launch(const T* z, const T* f, TO* o, const T* a1,
                               const TA2* a2, int C, int HW, int rev,
                               hipStream_t s)
{
    const long long tot = (long long)C * HW;
    fo_pool_k<T, TA2, TO><<<(unsigned)((tot + 255) / 256), 256, 0, s>>>(
        z, f, o, a1, a2, C, HW, rev);
}

// ---------------------------------------------------------------------------
// Memory plan (units of U = one @256 channel). Pool = 56 U. No kernel ever
// has out aliasing one of its inputs; slots reused only after last read.
// (Identical to the round-6 passing plan.)
// ---------------------------------------------------------------------------
template<typename T>
static void run_net(const float* x, const float* const* W, const float* const* B,
                    float* out, T* P, hipStream_t s)
{
    const T* np = nullptr;
    const T* np2 = nullptr;

    fill_k<T><<<2048, 256, 0, s>>>(P, POOL_UNITS * U);

    T* FE = P + 32 * U;
    // ---- fe = biqrnn(conv(x)) : 1 -> 48 gates -> 16 ch @256, chunks of 4 ---
    for (int a = 0; a < 16; a += 4) {
        conv_launch<float, T>(x, W[0], B[0], P,         1, a,      4, 256, 256, 256, 256, 1, false, s);
        conv_launch<float, T>(x, W[0], B[0], P + 4 * U, 1, 16 + a, 4, 256, 256, 256, 256, 1, false, s);
        conv_launch<float, T>(x, W[0], B[0], P + 8 * U, 1, 32 + a, 4, 256, 256, 256, 256, 1, false, s);
        pool_launch<T, T, T>(P, P + 4 * U, P + 12 * U, np, np2, 4, 65536, 0, s);
        pool_launch<T, T, T>(P, P + 8 * U, FE + (size_t)a * U, P + 12 * U, np2, 4, 65536, 1, s);
    }

    // ---- e0 = qrnn(conv(fe), fwd) : 16 -> 32 -> 16 @256, chunks of 8 -------
    T* E0 = P + 16 * U;
    for (int a = 0; a < 16; a += 8) {
        conv_launch<T, T>(FE, W[1], B[1], P,         16, a,      8, 256, 256, 256, 256, 1, false, s);
        conv_launch<T, T>(FE, W[1], B[1], P + 8 * U, 16, 16 + a, 8, 256, 256, 256, 256, 1, false, s);
        pool_launch<T, T, T>(P, P + 8 * U, E0 + (size_t)a * U, np, np2, 8, 65536, 0, s);
    }
    // FE dead (recomputed later).

    // ---- e1 = qrnn(conv(e0, s2), rev) : 16 -> 64 -> 32 @128 ----------------
    T* E1 = P;
    {
        T* G = P + 32 * U;
        conv_launch<T, T>(E0, W[2], B[2], G, 16, 0, 64, 256, 256, 128, 128, 2, false, s);
        pool_launch<T, T, T>(G, G + 8 * U, E1, np, np2, 32, 16384, 1, s);
    }

    // ---- e2 = qrnn(conv(e1), fwd) : 32 -> 64 -> 32 @128 --------------------
    T* E2 = P + 8 * U;
    {
        T* G = P + 32 * U;
        conv_launch<T, T>(E1, W[3], B[3], G, 32, 0, 64, 128, 128, 128, 128, 1, false, s);
        pool_launch<T, T, T>(G, G + 8 * U, E2, np, np2, 32, 16384, 0, s);
    }

    // ---- e3 = qrnn(conv(e2, s2), rev) : 32 -> 128 -> 64 @64 ----------------
    T* E3 = P + 32 * U;
    {
        T* G = P + 48 * U;
        conv_launch<T, T>(E2, W[4], B[4], G, 32, 0, 128, 128, 128, 64, 64, 2, false, s);
        pool_launch<T, T, T>(G, G + 4 * U, E3, np, np2, 64, 4096, 1, s);
    }

    // ---- e4 = qrnn(conv(e3), fwd) : 64 -> 128 -> 64 @64 --------------------
    T* E4 = P + 40 * U;
    {
        T* G = P + 48 * U;
        conv_launch<T, T>(E3, W[5], B[5], G, 64, 0, 128, 64, 64, 64, 64, 1, false, s);
        pool_launch<T, T, T>(G, G + 4 * U, E4, np, np2, 64, 4096, 0, s);
    }

    // ---- d0 = qrnn(deconv(e4), rev) : 64 -> 128 -> 64 @64 ------------------
    T* D0 = P + 44 * U;
    {
        T* G = P + 48 * U;
        conv_launch<T, T>(E4, W[6], B[6], G, 64, 0, 128, 64, 64, 64, 64, 1, true, s);
        pool_launch<T, T, T>(G, G + 4 * U, D0, np, np2, 64, 4096, 1, s);
    }
    // E4 dead.

    // ---- d1 = qrnn(conv(up(d0+e3)), fwd) + e2 : 64 -> 64 -> 32 @128 --------
    T* D1 = P + 36 * U;
    for (int a = 0; a < 32; a += 8) {
        T* G = P + 48 * U;  // z 8ch@V2=2U, f 2U
        conv_up_launch<T>(D0, E3, W[7], B[7], G,         64, a,      8, 64, 64, s);
        conv_up_launch<T>(D0, E3, W[7], B[7], G + 2 * U, 64, 32 + a, 8, 64, 64, s);
        pool_launch<T, T, T>(G, G + 2 * U, D1 + (size_t)a * V2,
                             E2 + (size_t)a * V2, np2, 8, 16384, 0, s);
    }
    // E2, E3, D0 dead.

    // ---- d2 = qrnn(deconv(d1), rev) : 32 -> 64 -> 32 @128 ------------------
    T* D2 = P + 8 * U;  // over dead E2
    for (int a = 0; a < 32; a += 16) {
        T* G = P + 48 * U;  // z 16ch@V2=4U, f 4U
        conv_launch<T, T>(D1, W[8], B[8], G,         32, a,      16, 128, 128, 128, 128, 1, true, s);
        conv_launch<T, T>(D1, W[8], B[8], G + 4 * U, 32, 32 + a, 16, 128, 128, 128, 128, 1, true, s);
        pool_launch<T, T, T>(G, G + 4 * U, D2 + (size_t)a * V2, np, np2, 16, 16384, 1, s);
    }
    // D1 dead.

    // ---- d3 = qrnn(conv(up(d2+e1)), fwd) + e0 : 32 -> 32 -> 16 @256 --------
    T* D3 = P + 32 * U;  // fresh 16U
    for (int a = 0; a < 16; a += 4) {
        T* G = P + 48 * U;  // z 4ch@U=4U, f 4U
        conv_up_launch<T>(D2, E1, W[9], B[9], G,         32, a,      4, 128, 128, s);
        conv_up_launch<T>(D2, E1, W[9], B[9], G + 4 * U, 32, 16 + a, 4, 128, 128, s);
        pool_launch<T, T, T>(G, G + 4 * U, D3 + (size_t)a * U,
                             E0 + (size_t)a * U, np2, 4, 65536, 0, s);
    }
    // E0, E1, D2 dead.

    // ---- recompute fe -> FE2 = [0,16), gates at [16,32) --------------------
    T* FE2 = P;
    for (int a = 0; a < 16; a += 4) {
        T* G = P + 16 * U;
        conv_launch<float, T>(x, W[0], B[0], G,         1, a,      4, 256, 256, 256, 256, 1, false, s);
        conv_launch<float, T>(x, W[0], B[0], G + 4 * U, 1, 16 + a, 4, 256, 256, 256, 256, 1, false, s);
        conv_launch<float, T>(x, W[0], B[0], G + 8 * U, 1, 32 + a, 4, 256, 256, 256, 256, 1, false, s);
        pool_launch<T, T, T>(G, G + 4 * U, G + 12 * U, np, np2, 4, 65536, 0, s);
        pool_launch<T, T, T>(G, G + 8 * U, FE2 + (size_t)a * U, G + 12 * U, np2, 4, 65536, 1, s);
    }

    // ---- d4 = qrnn(deconv(d3), rev) + fe : 16 -> 32 -> 16 @256 -------------
    T* D4 = P + 16 * U;  // fresh (over dead FE2-gates region)
    for (int a = 0; a < 16; a += 4) {
        T* G = P + 48 * U;
        conv_launch<T, T>(D3, W[10], B[10], G,         16, a,      4, 256, 256, 256, 256, 1, true, s);
        conv_launch<T, T>(D3, W[10], B[10], G + 4 * U, 16, 16 + a, 4, 256, 256, 256, 256, 1, true, s);
        pool_launch<T, T, T>(G, G + 4 * U, D4 + (size_t)a * U,
                             FE2 + (size_t)a * U, np2, 4, 65536, 1, s);
    }
    // D3, FE2 dead.

    // ---- out = biqrnn(deconv(d4)) + x : 16 -> 3 -> 1 @256 -> fp32 d_out ----
    {
        T* G = P + 32 * U;     // ch0 z, ch1 f1, ch2 f2
        T* TMP = P + 35 * U;
        conv_launch<T, T>(D4, W[11], B[11], G, 16, 0, 3, 256, 256, 256, 256, 1, true, s);
        pool_launch<T, T, T>(G, G + 1 * U, TMP, np, np2, 1, 65536, 0, s);
        pool_launch<T, float, float>(G, G + 2 * U, out, TMP, x, 1, 65536, 1, s);
    }
}

extern "C" void kernel_launch(void* const* d_in, const int* in_sizes, int n_in,
                              void* d_out, int out_size, void* d_ws, size_t ws_size,
                              hipStream_t stream)
{
    const float* x = (const float*)d_in[0];
    const float* W[12];
    const float* B[12];
    for (int i = 0; i < 12; ++i) {
        W[i] = (const float*)d_in[1 + 2 * i];
        B[i] = (const float*)d_in[2 + 2 * i];
    }

    const size_t need_f32 = (size_t)(POOL_UNITS * U) * sizeof(float);  // ~455 MB
    const size_t need_b16 = (size_t)(POOL_UNITS * U) * sizeof(bf16);   // ~227 MB
    if (ws_size >= need_f32) {
        run_net<float>(x, W, B, (float*)d_out, (float*)d_ws, stream);
    } else if (ws_size >= need_b16) {
        run_net<bf16>(x, W, B, (float*)d_out, (bf16*)d_ws, stream);
    } else {
        const float ws_mb = (float)((double)ws_size / 1048576.0);
        diag_k<<<(out_size + 255) / 256, 256, 0, stream>>>(
            (float*)d_out, ws_mb, out_size);
    }
}

// Round 8
// 20077.094 us; speedup vs baseline: 3.4239x; 1.2316x over previous
//
#include <hip/hip_runtime.h>
#include <hip/hip_bf16.h>
#include <cstdint>
#include <cstddef>

using bf16 = __hip_bfloat16;

static constexpr int DD = 31;                      // depth (time) extent
static constexpr long long U  = 31LL * 256 * 256;  // 2,031,616 elems (1 ch @256)
static constexpr long long V2 = 31LL * 128 * 128;  //   507,904 (1 ch @128)
static constexpr long long V3 = 31LL * 64 * 64;    //   126,976 (1 ch @64)
static constexpr long long POOL_UNITS = 56;        // pool = 56*U elems
static constexpr int CI_CHUNK = 32;                // LDS weight-staging chunk

__device__ __forceinline__ float toF(float v) { return v; }
__device__ __forceinline__ float toF(bf16 v) { return __bfloat162float(v); }
__device__ __forceinline__ void stv(float* p, float v) { *p = v; }
__device__ __forceinline__ void stv(bf16* p, float v) { *p = __float2bfloat16(v); }
__device__ __forceinline__ float sigm(float x) { return 1.f / (1.f + __expf(-x)); }

// ---------------------------------------------------------------------------
template<typename T>
__global__ __launch_bounds__(256)
void fill_k(T* p, long long n)
{
    const long long stride = (long long)gridDim.x * 256;
    for (long long i = (long long)blockIdx.x * 256 + threadIdx.x; i < n; i += stride)
        stv(p + i, 0.f);
}

// ---------------------------------------------------------------------------
// Direct 3D conv, kernel 3x3x3, pad 1, CO_BLK output channels per block.
// Each thread computes 4 consecutive-w outputs for CO_BLK channels: 6 window
// loads per (ci,kd,kh) feed 12*CO_BLK FMAs. Weights staged in LDS in ci-chunks
// of CI_CHUNK (caps LDS at 27.6 KB -> >=4 blocks/CU), transposed to
// [ci*27+k][CO_BLK] so inner reads are CO_BLK-contiguous. FLIP at staging.
// Requires DD*Hout*Wout % 1024 == 0, Wout % 4 == 0. STRIDE==1 -> Win==Wout.
// ---------------------------------------------------------------------------
template<typename TIN, typename T, int STRIDE, bool FLIP, int CO_BLK>
__global__ __launch_bounds__(256)
void conv3d_k(const TIN* __restrict__ in, const float* __restrict__ wt,
              const float* __restrict__ bias, T* __restrict__ out,
              int Cin, int Hin, int Win, int Hout, int Wout)
{
    extern __shared__ float wl[];  // [CI_CHUNK*27][CO_BLK]
    const int co_base = blockIdx.y * CO_BLK;

    const int s4 = (blockIdx.x * 256 + threadIdx.x) * 4;
    const int w0 = s4 % Wout;
    const int sh = s4 / Wout;
    const int h0 = sh % Hout;
    const int d0 = sh / Hout;

    float acc[CO_BLK][4];
#pragma unroll
    for (int j = 0; j < CO_BLK; ++j) {
        const float bv = bias[co_base + j];
        acc[j][0] = bv; acc[j][1] = bv; acc[j][2] = bv; acc[j][3] = bv;
    }

    const size_t HWin = (size_t)Hin * Win;
    constexpr int WL = 3 * STRIDE + 3;  // input window covering 4 outputs

    for (int ci0 = 0; ci0 < Cin; ci0 += CI_CHUNK) {
        const int cn = (Cin - ci0 < CI_CHUNK) ? (Cin - ci0) : CI_CHUNK;
        __syncthreads();  // protect LDS reuse from previous chunk
        for (int t = threadIdx.x; t < cn * 27 * CO_BLK; t += 256) {
            const int j = t % CO_BLK;
            const int klin = t / CO_BLK;
            const int ci = klin / 27;
            const int r = klin % 27;
            int src;
            if (FLIP) {
                const int kd = r / 9, kh = (r / 3) % 3, kw = r % 3;
                src = (2 - kd) * 9 + (2 - kh) * 3 + (2 - kw);
            } else {
                src = r;
            }
            wl[t] = wt[((size_t)(co_base + j) * Cin + (ci0 + ci)) * 27 + src];
        }
        __syncthreads();

        for (int ci = 0; ci < cn; ++ci) {
            const TIN* cb = in + (size_t)(ci0 + ci) * DD * HWin;
            const float* wc = wl + ci * 27 * CO_BLK;
#pragma unroll
            for (int kd = 0; kd < 3; ++kd) {
                const int di = d0 + kd - 1;
                if (di < 0 || di >= DD) continue;
#pragma unroll
                for (int kh = 0; kh < 3; ++kh) {
                    const int hi = h0 * STRIDE + kh - 1;
                    if (hi < 0 || hi >= Hin) continue;
                    const TIN* row = cb + (size_t)di * HWin + (size_t)hi * Win
                                     + (size_t)w0 * STRIDE;
                    float v[WL];
                    v[0] = (w0 > 0) ? toF(row[-1]) : 0.f;
#pragma unroll
                    for (int t = 1; t < WL - 1; ++t) v[t] = toF(row[t - 1]);
                    if (STRIDE == 1) {
                        v[WL - 1] = (w0 + 4 < Win) ? toF(row[WL - 2]) : 0.f;
                    } else {
                        v[WL - 1] = toF(row[WL - 2]);  // 2*w0+7 <= Win-1 always
                    }
                    const float* wk = wc + (kd * 9 + kh * 3) * CO_BLK;
#pragma unroll
                    for (int kw = 0; kw < 3; ++kw) {
#pragma unroll
                        for (int j = 0; j < CO_BLK; ++j) {
                            const float wv = wk[kw * CO_BLK + j];
                            acc[j][0] = fmaf(v[0 * STRIDE + kw], wv, acc[j][0]);
                            acc[j][1] = fmaf(v[1 * STRIDE + kw], wv, acc[j][1]);
                            acc[j][2] = fmaf(v[2 * STRIDE + kw], wv, acc[j][2]);
                            acc[j][3] = fmaf(v[3 * STRIDE + kw], wv, acc[j][3]);
                        }
                    }
                }
            }
        }
    }
#pragma unroll
    for (int j = 0; j < CO_BLK; ++j) {
        T* op = out + (((size_t)(co_base + j) * DD + d0) * Hout + h0) * Wout + w0;
        stv(op + 0, acc[j][0]); stv(op + 1, acc[j][1]);
        stv(op + 2, acc[j][2]); stv(op + 3, acc[j][3]);
    }
}

// ---------------------------------------------------------------------------
// Fused: conv3d( upsample2x(a + b) ), stride 1, no flip, CO_BLK channels per
// block, ci-chunked LDS staging. a,b half-res; out [nCo, DD, 2*Hlo, 2*Wlo].
// ---------------------------------------------------------------------------
template<typename T, int CO_BLK>
__global__ __launch_bounds__(256)
void conv3d_up_k(const T* __restrict__ ia, const T* __restrict__ ib,
                 const float* __restrict__ wt, const float* __restrict__ bias,
                 T* __restrict__ out, int Cin, int Hlo, int Wlo)
{
    extern __shared__ float wl[];  // [CI_CHUNK*27][CO_BLK]
    const int co_base = blockIdx.y * CO_BLK;

    const int Hout = 2 * Hlo, Wout = 2 * Wlo;
    const int s4 = (blockIdx.x * 256 + threadIdx.x) * 4;
    const int w0 = s4 % Wout;                  // multiple of 4
    const int sh = s4 / Wout;
    const int h0 = sh % Hout;
    const int d0 = sh / Hout;
    const int lw = w0 >> 1;

    float acc[CO_BLK][4];
#pragma unroll
    for (int j = 0; j < CO_BLK; ++j) {
        const float bv = bias[co_base + j];
        acc[j][0] = bv; acc[j][1] = bv; acc[j][2] = bv; acc[j][3] = bv;
    }
    const size_t HWlo = (size_t)Hlo * Wlo;

    for (int ci0 = 0; ci0 < Cin; ci0 += CI_CHUNK) {
        const int cn = (Cin - ci0 < CI_CHUNK) ? (Cin - ci0) : CI_CHUNK;
        __syncthreads();
        for (int t = threadIdx.x; t < cn * 27 * CO_BLK; t += 256) {
            const int j = t % CO_BLK;
            const int klin = t / CO_BLK;
            const int ci = klin / 27;
            const int r = klin % 27;
            wl[t] = wt[((size_t)(co_base + j) * Cin + (ci0 + ci)) * 27 + r];
        }
        __syncthreads();

        for (int ci = 0; ci < cn; ++ci) {
            const T* cba = ia + (size_t)(ci0 + ci) * DD * HWlo;
            const T* cbb = ib + (size_t)(ci0 + ci) * DD * HWlo;
            const float* wc = wl + ci * 27 * CO_BLK;
#pragma unroll
            for (int kd = 0; kd < 3; ++kd) {
                const int di = d0 + kd - 1;
                if (di < 0 || di >= DD) continue;
#pragma unroll
                for (int kh = 0; kh < 3; ++kh) {
                    const int hi = h0 + kh - 1;
                    if (hi < 0 || hi >= Hout) continue;
                    const int hlo = hi >> 1;
                    const T* ra = cba + (size_t)di * HWlo + (size_t)hlo * Wlo;
                    const T* rb = cbb + (size_t)di * HWlo + (size_t)hlo * Wlo;
                    float u[4];
#pragma unroll
                    for (int jj = 0; jj < 4; ++jj) {
                        const int lj = lw - 1 + jj;
                        u[jj] = (lj >= 0 && lj < Wlo) ? (toF(ra[lj]) + toF(rb[lj])) : 0.f;
                    }
                    // upsampled window: w0-1 .. w0+4
                    const float v0 = u[0], v1 = u[1], v2 = u[1], v3 = u[2],
                                v4 = u[2], v5 = u[3];
                    const float* wk = wc + (kd * 9 + kh * 3) * CO_BLK;
#pragma unroll
                    for (int j = 0; j < CO_BLK; ++j) {
                        const float q0 = wk[0 * CO_BLK + j];
                        const float q1 = wk[1 * CO_BLK + j];
                        const float q2 = wk[2 * CO_BLK + j];
                        acc[j][0] = fmaf(v0, q0, fmaf(v1, q1, fmaf(v2, q2, acc[j][0])));
                        acc[j][1] = fmaf(v1, q0, fmaf(v2, q1, fmaf(v3, q2, acc[j][1])));
                        acc[j][2] = fmaf(v2, q0, fmaf(v3, q1, fmaf(v4, q2, acc[j][2])));
                        acc[j][3] = fmaf(v3, q0, fmaf(v4, q1, fmaf(v5, q2, acc[j][3])));
                    }
                }
            }
        }
    }
#pragma unroll
    for (int j = 0; j < CO_BLK; ++j) {
        T* op = out + (((size_t)(co_base + j) * DD + d0) * Hout + h0) * Wout + w0;
        stv(op + 0, acc[j][0]); stv(op + 1, acc[j][1]);
        stv(op + 2, acc[j][2]); stv(op + 3, acc[j][3]);
    }
}

// ---------------------------------------------------------------------------
// fo_pool over D=31. z/f are per-channel [C, D, HW] bases (explicit ptrs).
// out[off] = h_d + a1[off]? + a2[off]?   (a1/a2 nullable). No aliasing used.
// ---------------------------------------------------------------------------
template<typename T, typename TA2, typename TO>
__global__ __launch_bounds__(256)
void fo_pool_k(const T* __restrict__ z, const T* __restrict__ f,
               TO* __restrict__ out, const T* __restrict__ a1,
               const TA2* __restrict__ a2, int C, int HW, int reverse)
{
    const long long idx = (long long)blockIdx.x * 256 + threadIdx.x;
    const int c = (int)(idx / HW);
    if (c >= C) return;
    const int p = (int)(idx - (long long)c * HW);
    const size_t base = (size_t)c * DD * HW + p;
    float h = 0.f;
    if (!reverse) {
        for (int d = 0; d < DD; ++d) {
            const size_t off = base + (size_t)d * HW;
            const float zz = tanhf(toF(z[off]));
            const float ff = sigm(toF(f[off]));
            h = ff * h + (1.f - ff) * zz;
            float v = h;
            if (a1) v += toF(a1[off]);
            if (a2) v += toF(a2[off]);
            stv(out + off, v);
        }
    } else {
        for (int d = DD - 1; d >= 0; --d) {
            const size_t off = base + (size_t)d * HW;
            const float zz = tanhf(toF(z[off]));
            const float ff = sigm(toF(f[off]));
            h = ff * h + (1.f - ff) * zz;
            float v = h;
            if (a1) v += toF(a1[off]);
            if (a2) v += toF(a2[off]);
            stv(out + off, v);
        }
    }
}

// Diagnostic: encode ws_size (MB) into output if workspace too small.
__global__ __launch_bounds__(256)
void diag_k(float* out, float v, int n)
{
    const int i = blockIdx.x * 256 + threadIdx.x;
    if (i < n) out[i] = v;
}

// ---------------------------------------------------------------------------

template<typename TIN, typename T>
static inline void conv_launch(const TIN* in, const float* w, const float* b,
                               T* out, int Cin, int co0, int nCo,
                               int Hin, int Win, int Hout, int Wout,
                               int stride, bool flip, hipStream_t s)
{
    const unsigned gx = (unsigned)((DD * (long long)Hout * Wout) / 1024);
    const float* wp = w + (size_t)co0 * Cin * 27;
    const float* bp = b + co0;
    const int cic = (Cin < CI_CHUNK) ? Cin : CI_CHUNK;
    if (stride == 2) {
        if (nCo % 8 == 0) {
            dim3 grid(gx, nCo / 8);
            conv3d_k<TIN, T, 2, false, 8><<<grid, 256, (size_t)cic * 27 * 8 * 4, s>>>(
                in, wp, bp, out, Cin, Hin, Win, Hout, Wout);
        } else {
            dim3 grid(gx, nCo / 4);
            conv3d_k<TIN, T, 2, false, 4><<<grid, 256, (size_t)cic * 27 * 4 * 4, s>>>(
                in, wp, bp, out, Cin, Hin, Win, Hout, Wout);
        }
    } else if (flip) {
        if (nCo % 8 == 0) {
            dim3 grid(gx, nCo / 8);
            conv3d_k<TIN, T, 1, true, 8><<<grid, 256, (size_t)cic * 27 * 8 * 4, s>>>(
                in, wp, bp, out, Cin, Hin, Win, Hout, Wout);
        } else if (nCo % 4 == 0) {
            dim3 grid(gx, nCo / 4);
            conv3d_k<TIN, T, 1, true, 4><<<grid, 256, (size_t)cic * 27 * 4 * 4, s>>>(
                in, wp, bp, out, Cin, Hin, Win, Hout, Wout);
        } else {  // rec layer: nCo == 3
            dim3 grid(gx, nCo / 3);
            conv3d_k<TIN, T, 1, true, 3><<<grid, 256, (size_t)cic * 27 * 3 * 4, s>>>(
                in, wp, bp, out, Cin, Hin, Win, Hout, Wout);
        }
    } else {
        if (nCo % 8 == 0) {
            dim3 grid(gx, nCo / 8);
            conv3d_k<TIN, T, 1, false, 8><<<grid, 256, (size_t)cic * 27 * 8 * 4, s>>>(
                in, wp, bp, out, Cin, Hin, Win, Hout, Wout);
        } else {
            dim3 grid(gx, nCo / 4);
            conv3d_k<TIN, T, 1, false, 4><<<grid, 256, (size_t)cic * 27 * 4 * 4, s>>>(
                in, wp, bp, out, Cin, Hin, Win, Hout, Wout);
        }
    }
}

template<typename T>
static inline void conv_up_launch(const T* ia, const T* ib, const float* w,
                                  const float* b, T* out, int Cin, int co0,
                                  int nCo, int Hlo, int Wlo, hipStream_t s)
{
    const unsigned gx = (unsigned)((DD * 4LL * Hlo * Wlo) / 1024);
    const int cic = (Cin < CI_CHUNK) ? Cin : CI_CHUNK;
    if (nCo % 8 == 0) {
        dim3 grid(gx, nCo / 8);
        conv3d_up_k<T, 8><<<grid, 256, (size_t)cic * 27 * 8 * 4, s>>>(
            ia, ib, w + (size_t)co0 * Cin * 27, b + co0, out, Cin, Hlo, Wlo);
    } else {
        dim3 grid(gx, nCo / 4);
        conv3d_up_k<T, 4><<<grid, 256, (size_t)cic * 27 * 4 * 4, s>>>(
            ia, ib, w + (size_t)co0 * Cin * 27, b + co0, out, Cin, Hlo, Wlo);
    }
}

template<typename T, typename TA2, typename TO>
static inline void pool_launch(const T* z, const T* f, TO* o, const T* a1,
                               const TA2* a2, int C, int HW, int rev,
                               hipStream_t s)
{
    const long long tot = (long long)C * HW;
    fo_pool_k<T, TA2, TO><<<(unsigned)((tot + 255) / 256), 256, 0, s>>>(
        z, f, o, a1, a2, C, HW, rev);
}

// ---------------------------------------------------------------------------
// Memory plan (units of U = one @256 channel). Pool = 56 U. No kernel ever
// has out aliasing one of its inputs; slots reused only after last read.
// (Identical to the round-6/7 passing plan.)
// ---------------------------------------------------------------------------
template<typename T>
static void run_net(const float* x, const float* const* W, const float* const* B,
                    float* out, T* P, hipStream_t s)
{
    const T* np = nullptr;
    const T* np2 = nullptr;

    fill_k<T><<<2048, 256, 0, s>>>(P, POOL_UNITS * U);

    T* FE = P + 32 * U;
    // ---- fe = biqrnn(conv(x)) : 1 -> 48 gates -> 16 ch @256, chunks of 4 ---
    for (int a = 0; a < 16; a += 4) {
        conv_launch<float, T>(x, W[0], B[0], P,         1, a,      4, 256, 256, 256, 256, 1, false, s);
        conv_launch<float, T>(x, W[0], B[0], P + 4 * U, 1, 16 + a, 4, 256, 256, 256, 256, 1, false, s);
        conv_launch<float, T>(x, W[0], B[0], P + 8 * U, 1, 32 + a, 4, 256, 256, 256, 256, 1, false, s);
        pool_launch<T, T, T>(P, P + 4 * U, P + 12 * U, np, np2, 4, 65536, 0, s);
        pool_launch<T, T, T>(P, P + 8 * U, FE + (size_t)a * U, P + 12 * U, np2, 4, 65536, 1, s);
    }

    // ---- e0 = qrnn(conv(fe), fwd) : 16 -> 32 -> 16 @256, chunks of 8 -------
    T* E0 = P + 16 * U;
    for (int a = 0; a < 16; a += 8) {
        conv_launch<T, T>(FE, W[1], B[1], P,         16, a,      8, 256, 256, 256, 256, 1, false, s);
        conv_launch<T, T>(FE, W[1], B[1], P + 8 * U, 16, 16 + a, 8, 256, 256, 256, 256, 1, false, s);
        pool_launch<T, T, T>(P, P + 8 * U, E0 + (size_t)a * U, np, np2, 8, 65536, 0, s);
    }
    // FE dead (recomputed later).

    // ---- e1 = qrnn(conv(e0, s2), rev) : 16 -> 64 -> 32 @128 ----------------
    T* E1 = P;
    {
        T* G = P + 32 * U;
        conv_launch<T, T>(E0, W[2], B[2], G, 16, 0, 64, 256, 256, 128, 128, 2, false, s);
        pool_launch<T, T, T>(G, G + 8 * U, E1, np, np2, 32, 16384, 1, s);
    }

    // ---- e2 = qrnn(conv(e1), fwd) : 32 -> 64 -> 32 @128 --------------------
    T* E2 = P + 8 * U;
    {
        T* G = P + 32 * U;
        conv_launch<T, T>(E1, W[3], B[3], G, 32, 0, 64, 128, 128, 128, 128, 1, false, s);
        pool_launch<T, T, T>(G, G + 8 * U, E2, np, np2, 32, 16384, 0, s);
    }

    // ---- e3 = qrnn(conv(e2, s2), rev) : 32 -> 128 -> 64 @64 ----------------
    T* E3 = P + 32 * U;
    {
        T* G = P + 48 * U;
        conv_launch<T, T>(E2, W[4], B[4], G, 32, 0, 128, 128, 128, 64, 64, 2, false, s);
        pool_launch<T, T, T>(G, G + 4 * U, E3, np, np2, 64, 4096, 1, s);
    }

    // ---- e4 = qrnn(conv(e3), fwd) : 64 -> 128 -> 64 @64 --------------------
    T* E4 = P + 40 * U;
    {
        T* G = P + 48 * U;
        conv_launch<T, T>(E3, W[5], B[5], G, 64, 0, 128, 64, 64, 64, 64, 1, false, s);
        pool_launch<T, T, T>(G, G + 4 * U, E4, np, np2, 64, 4096, 0, s);
    }

    // ---- d0 = qrnn(deconv(e4), rev) : 64 -> 128 -> 64 @64 ------------------
    T* D0 = P + 44 * U;
    {
        T* G = P + 48 * U;
        conv_launch<T, T>(E4, W[6], B[6], G, 64, 0, 128, 64, 64, 64, 64, 1, true, s);
        pool_launch<T, T, T>(G, G + 4 * U, D0, np, np2, 64, 4096, 1, s);
    }
    // E4 dead.

    // ---- d1 = qrnn(conv(up(d0+e3)), fwd) + e2 : 64 -> 64 -> 32 @128 --------
    T* D1 = P + 36 * U;
    for (int a = 0; a < 32; a += 8) {
        T* G = P + 48 * U;  // z 8ch@V2=2U, f 2U
        conv_up_launch<T>(D0, E3, W[7], B[7], G,         64, a,      8, 64, 64, s);
        conv_up_launch<T>(D0, E3, W[7], B[7], G + 2 * U, 64, 32 + a, 8, 64, 64, s);
        pool_launch<T, T, T>(G, G + 2 * U, D1 + (size_t)a * V2,
                             E2 + (size_t)a * V2, np2, 8, 16384, 0, s);
    }
    // E2, E3, D0 dead.

    // ---- d2 = qrnn(deconv(d1), rev) : 32 -> 64 -> 32 @128 ------------------
    T* D2 = P + 8 * U;  // over dead E2
    for (int a = 0; a < 32; a += 16) {
        T* G = P + 48 * U;  // z 16ch@V2=4U, f 4U
        conv_launch<T, T>(D1, W[8], B[8], G,         32, a,      16, 128, 128, 128, 128, 1, true, s);
        conv_launch<T, T>(D1, W[8], B[8], G + 4 * U, 32, 32 + a, 16, 128, 128, 128, 128, 1, true, s);
        pool_launch<T, T, T>(G, G + 4 * U, D2 + (size_t)a * V2, np, np2, 16, 16384, 1, s);
    }
    // D1 dead.

    // ---- d3 = qrnn(conv(up(d2+e1)), fwd) + e0 : 32 -> 32 -> 16 @256 --------
    T* D3 = P + 32 * U;  // fresh 16U
    for (int a = 0; a < 16; a += 4) {
        T* G = P + 48 * U;  // z 4ch@U=4U, f 4U
        conv_up_launch<T>(D2, E1, W[9], B[9], G,         32, a,      4, 128, 128, s);
        conv_up_launch<T>(D2, E1, W[9], B[9], G + 4 * U, 32, 16 + a, 4, 128, 128, s);
        pool_launch<T, T, T>(G, G + 4 * U, D3 + (size_t)a * U,
                             E0 + (size_t)a * U, np2, 4, 65536, 0, s);
    }
    // E0, E1, D2 dead.

    // ---- recompute fe -> FE2 = [0,16), gates at [16,32) --------------------
    T* FE2 = P;
    for (int a = 0; a < 16; a += 4) {
        T* G = P + 16 * U;
        conv_launch<float, T>(x, W[0], B[0], G,         1, a,      4, 256, 256, 256, 256, 1, false, s);
        conv_launch<float, T>(x, W[0], B[0], G + 4 * U, 1, 16 + a, 4, 256, 256, 256, 256, 1, false, s);
        conv_launch<float, T>(x, W[0], B[0], G + 8 * U, 1, 32 + a, 4, 256, 256, 256, 256, 1, false, s);
        pool_launch<T, T, T>(G, G + 4 * U, G + 12 * U, np, np2, 4, 65536, 0, s);
        pool_launch<T, T, T>(G, G + 8 * U, FE2 + (size_t)a * U, G + 12 * U, np2, 4, 65536, 1, s);
    }

    // ---- d4 = qrnn(deconv(d3), rev) + fe : 16 -> 32 -> 16 @256 -------------
    T* D4 = P + 16 * U;  // fresh (over dead FE2-gates region)
    for (int a = 0; a < 16; a += 4) {
        T* G = P + 48 * U;
        conv_launch<T, T>(D3, W[10], B[10], G,         16, a,      4, 256, 256, 256, 256, 1, true, s);
        conv_launch<T, T>(D3, W[10], B[10], G + 4 * U, 16, 16 + a, 4, 256, 256, 256, 256, 1, true, s);
        pool_launch<T, T, T>(G, G + 4 * U, D4 + (size_t)a * U,
                             FE2 + (size_t)a * U, np2, 4, 65536, 1, s);
    }
    // D3, FE2 dead.

    // ---- out = biqrnn(deconv(d4)) + x : 16 -> 3 -> 1 @256 -> fp32 d_out ----
    {
        T* G = P + 32 * U;     // ch0 z, ch1 f1, ch2 f2
        T* TMP = P + 35 * U;
        conv_launch<T, T>(D4, W[11], B[11], G, 16, 0, 3, 256, 256, 256, 256, 1, true, s);
        pool_launch<T, T, T>(G, G + 1 * U, TMP, np, np2, 1, 65536, 0, s);
        pool_launch<T, float, float>(G, G + 2 * U, out, TMP, x, 1, 65536, 1, s);
    }
}

extern "C" void kernel_launch(void* const* d_in, const int* in_sizes, int n_in,
                              void* d_out, int out_size, void* d_ws, size_t ws_size,
                              hipStream_t stream)
{
    const float* x = (const float*)d_in[0];
    const float* W[12];
    const float* B[12];
    for (int i = 0; i < 12; ++i) {
        W[i] = (const float*)d_in[1 + 2 * i];
        B[i] = (const float*)d_in[2 + 2 * i];
    }

    const size_t need_f32 = (size_t)(POOL_UNITS * U) * sizeof(float);  // ~455 MB
    const size_t need_b16 = (size_t)(POOL_UNITS * U) * sizeof(bf16);   // ~227 MB
    if (ws_size >= need_f32) {
        run_net<float>(x, W, B, (float*)d_out, (float*)d_ws, stream);
    } else if (ws_size >= need_b16) {
        run_net<bf16>(x, W, B, (float*)d_out, (bf16*)d_ws, stream);
    } else {
        const float ws_mb = (float)((double)ws_size / 1048576.0);
        diag_k<<<(out_size + 255) / 256, 256, 0, stream>>>(
            (float*)d_out, ws_mb, out_size);
    }
}

// Round 9
// 12340.737 us; speedup vs baseline: 5.5703x; 1.6269x over previous
//
#include <hip/hip_runtime.h>
#include <hip/hip_bf16.h>
#include <cstdint>
#include <cstddef>

using bf16 = __hip_bfloat16;

static constexpr int DD = 31;                      // depth (time) extent
static constexpr long long U  = 31LL * 256 * 256;  // 2,031,616 elems (1 ch @256)
static constexpr long long V2 = 31LL * 128 * 128;  //   507,904 (1 ch @128)
static constexpr long long V3 = 31LL * 64 * 64;    //   126,976 (1 ch @64)
static constexpr long long POOL_UNITS = 56;        // pool = 56*U elems
static constexpr int CI_CHUNK = 32;                // LDS weight-staging chunk

__device__ __forceinline__ float toF(float v) { return v; }
__device__ __forceinline__ float toF(bf16 v) { return __bfloat162float(v); }
__device__ __forceinline__ void stv(float* p, float v) { *p = v; }
__device__ __forceinline__ void stv(bf16* p, float v) { *p = __float2bfloat16(v); }
__device__ __forceinline__ float sigm(float x) { return 1.f / (1.f + __expf(-x)); }

// ---- vector load/store helpers (alignment guaranteed by layout: all channel
// bases are multiples of V3 = 31*4096 elems; w-offsets are multiples of 8) ----
__device__ __forceinline__ void load8f(const bf16* p, float* v)
{
    const uint4 q = *(const uint4*)p;
    v[0] = __uint_as_float(q.x << 16); v[1] = __uint_as_float(q.x & 0xffff0000u);
    v[2] = __uint_as_float(q.y << 16); v[3] = __uint_as_float(q.y & 0xffff0000u);
    v[4] = __uint_as_float(q.z << 16); v[5] = __uint_as_float(q.z & 0xffff0000u);
    v[6] = __uint_as_float(q.w << 16); v[7] = __uint_as_float(q.w & 0xffff0000u);
}
__device__ __forceinline__ void load8f(const float* p, float* v)
{
    const float4 a = *(const float4*)p;
    const float4 b = *(const float4*)(p + 4);
    v[0] = a.x; v[1] = a.y; v[2] = a.z; v[3] = a.w;
    v[4] = b.x; v[5] = b.y; v[6] = b.z; v[7] = b.w;
}
__device__ __forceinline__ void load4f(const bf16* p, float* v)
{
    const uint2 q = *(const uint2*)p;
    v[0] = __uint_as_float(q.x << 16); v[1] = __uint_as_float(q.x & 0xffff0000u);
    v[2] = __uint_as_float(q.y << 16); v[3] = __uint_as_float(q.y & 0xffff0000u);
}
__device__ __forceinline__ void load4f(const float* p, float* v)
{
    const float4 a = *(const float4*)p;
    v[0] = a.x; v[1] = a.y; v[2] = a.z; v[3] = a.w;
}
__device__ __forceinline__ void store8(bf16* p, const float* v)
{
    bf16 t[8];
#pragma unroll
    for (int o = 0; o < 8; ++o) t[o] = __float2bfloat16(v[o]);
    *(uint4*)p = *(const uint4*)t;
}
__device__ __forceinline__ void store8(float* p, const float* v)
{
    *(float4*)p = make_float4(v[0], v[1], v[2], v[3]);
    *(float4*)(p + 4) = make_float4(v[4], v[5], v[6], v[7]);
}

// ---------------------------------------------------------------------------
template<typename T>
__global__ __launch_bounds__(256)
void fill_k(T* p, long long n)
{
    const long long stride = (long long)gridDim.x * 256;
    for (long long i = (long long)blockIdx.x * 256 + threadIdx.x; i < n; i += stride)
        stv(p + i, 0.f);
}

// ---------------------------------------------------------------------------
// Direct 3D conv, 3x3x3, pad 1. W-tile = 8 (vector loads), CO_BLK out-channels
// per block. Per (ci,kd,kh): 1 uint4 + <=2 scalar loads feed 24*CO_BLK FMAs.
// Weights staged in LDS (ci-chunks of CI_CHUNK, [k][CO_BLK] layout, FLIP at
// staging). Requires DD*Hout*Wout % 2048 == 0, Wout % 8 == 0.
// ---------------------------------------------------------------------------
template<typename TIN, typename T, int STRIDE, bool FLIP, int CO_BLK>
__global__ __launch_bounds__(256)
void conv3d_k(const TIN* __restrict__ in, const float* __restrict__ wt,
              const float* __restrict__ bias, T* __restrict__ out,
              int Cin, int Hin, int Win, int Hout, int Wout)
{
    extern __shared__ float wl[];  // [CI_CHUNK*27][CO_BLK]
    const int co_base = blockIdx.y * CO_BLK;

    const int s8 = (blockIdx.x * 256 + threadIdx.x) * 8;
    const int w0 = s8 % Wout;
    const int sh = s8 / Wout;
    const int h0 = sh % Hout;
    const int d0 = sh / Hout;

    float acc[CO_BLK][8];
#pragma unroll
    for (int j = 0; j < CO_BLK; ++j) {
        const float bv = bias[co_base + j];
#pragma unroll
        for (int o = 0; o < 8; ++o) acc[j][o] = bv;
    }

    const size_t HWin = (size_t)Hin * Win;
    constexpr int WL = (STRIDE == 1) ? 10 : 17;  // window covering 8 outputs

    for (int ci0 = 0; ci0 < Cin; ci0 += CI_CHUNK) {
        const int cn = (Cin - ci0 < CI_CHUNK) ? (Cin - ci0) : CI_CHUNK;
        __syncthreads();
        for (int t = threadIdx.x; t < cn * 27 * CO_BLK; t += 256) {
            const int j = t % CO_BLK;
            const int klin = t / CO_BLK;
            const int ci = klin / 27;
            const int r = klin % 27;
            int src;
            if (FLIP) {
                const int kd = r / 9, kh = (r / 3) % 3, kw = r % 3;
                src = (2 - kd) * 9 + (2 - kh) * 3 + (2 - kw);
            } else {
                src = r;
            }
            wl[t] = wt[((size_t)(co_base + j) * Cin + (ci0 + ci)) * 27 + src];
        }
        __syncthreads();

        for (int ci = 0; ci < cn; ++ci) {
            const TIN* cb = in + (size_t)(ci0 + ci) * DD * HWin;
            const float* wc = wl + ci * 27 * CO_BLK;
#pragma unroll
            for (int kd = 0; kd < 3; ++kd) {
                const int di = d0 + kd - 1;
                if (di < 0 || di >= DD) continue;
#pragma unroll
                for (int kh = 0; kh < 3; ++kh) {
                    const int hi = h0 * STRIDE + kh - 1;
                    if (hi < 0 || hi >= Hin) continue;
                    const TIN* row = cb + (size_t)di * HWin + (size_t)hi * Win
                                     + (size_t)w0 * STRIDE;
                    float v[WL];
                    v[0] = (w0 > 0) ? toF(row[-1]) : 0.f;
                    if (STRIDE == 1) {
                        load8f(row, v + 1);
                        v[9] = (w0 + 8 < Win) ? toF(row[8]) : 0.f;
                    } else {
                        load8f(row, v + 1);       // 2*w0 .. 2*w0+7
                        load8f(row + 8, v + 9);   // 2*w0+8 .. 2*w0+15 (in-bounds)
                    }
                    const float* wk = wc + (kd * 9 + kh * 3) * CO_BLK;
#pragma unroll
                    for (int kw = 0; kw < 3; ++kw) {
#pragma unroll
                        for (int j = 0; j < CO_BLK; ++j) {
                            const float wv = wk[kw * CO_BLK + j];
#pragma unroll
                            for (int o = 0; o < 8; ++o)
                                acc[j][o] = fmaf(v[o * STRIDE + kw], wv, acc[j][o]);
                        }
                    }
                }
            }
        }
    }
#pragma unroll
    for (int j = 0; j < CO_BLK; ++j) {
        T* op = out + (((size_t)(co_base + j) * DD + d0) * Hout + h0) * Wout + w0;
        store8(op, acc[j]);
    }
}

// ---------------------------------------------------------------------------
// Fused conv3d( upsample2x(a + b) ), stride 1, no flip, W-tile = 8.
// Per (ci,kd,kh): 2 x load4 + <=4 scalar loads feed 24*CO_BLK FMAs.
// ---------------------------------------------------------------------------
template<typename T, int CO_BLK>
__global__ __launch_bounds__(256)
void conv3d_up_k(const T* __restrict__ ia, const T* __restrict__ ib,
                 const float* __restrict__ wt, const float* __restrict__ bias,
                 T* __restrict__ out, int Cin, int Hlo, int Wlo)
{
    extern __shared__ float wl[];  // [CI_CHUNK*27][CO_BLK]
    const int co_base = blockIdx.y * CO_BLK;

    const int Hout = 2 * Hlo, Wout = 2 * Wlo;
    const int s8 = (blockIdx.x * 256 + threadIdx.x) * 8;
    const int w0 = s8 % Wout;                  // multiple of 8
    const int sh = s8 / Wout;
    const int h0 = sh % Hout;
    const int d0 = sh / Hout;
    const int lw = w0 >> 1;                    // multiple of 4

    float acc[CO_BLK][8];
#pragma unroll
    for (int j = 0; j < CO_BLK; ++j) {
        const float bv = bias[co_base + j];
#pragma unroll
        for (int o = 0; o < 8; ++o) acc[j][o] = bv;
    }
    const size_t HWlo = (size_t)Hlo * Wlo;

    for (int ci0 = 0; ci0 < Cin; ci0 += CI_CHUNK) {
        const int cn = (Cin - ci0 < CI_CHUNK) ? (Cin - ci0) : CI_CHUNK;
        __syncthreads();
        for (int t = threadIdx.x; t < cn * 27 * CO_BLK; t += 256) {
            const int j = t % CO_BLK;
            const int klin = t / CO_BLK;
            const int ci = klin / 27;
            const int r = klin % 27;
            wl[t] = wt[((size_t)(co_base + j) * Cin + (ci0 + ci)) * 27 + r];
        }
        __syncthreads();

        for (int ci = 0; ci < cn; ++ci) {
            const T* cba = ia + (size_t)(ci0 + ci) * DD * HWlo;
            const T* cbb = ib + (size_t)(ci0 + ci) * DD * HWlo;
            const float* wc = wl + ci * 27 * CO_BLK;
#pragma unroll
            for (int kd = 0; kd < 3; ++kd) {
                const int di = d0 + kd - 1;
                if (di < 0 || di >= DD) continue;
#pragma unroll
                for (int kh = 0; kh < 3; ++kh) {
                    const int hi = h0 + kh - 1;
                    if (hi < 0 || hi >= Hout) continue;
                    const int hlo = hi >> 1;
                    const T* ra = cba + (size_t)di * HWlo + (size_t)hlo * Wlo;
                    const T* rb = cbb + (size_t)di * HWlo + (size_t)hlo * Wlo;
                    float u[6], t1[4], t2[4];
                    u[0] = (lw > 0) ? (toF(ra[lw - 1]) + toF(rb[lw - 1])) : 0.f;
                    load4f(ra + lw, t1);
                    load4f(rb + lw, t2);
#pragma unroll
                    for (int q = 0; q < 4; ++q) u[1 + q] = t1[q] + t2[q];
                    u[5] = (lw + 4 < Wlo) ? (toF(ra[lw + 4]) + toF(rb[lw + 4])) : 0.f;
                    // upsampled window v[t] <-> up-w = w0-1+t, t in [0,10)
                    const float v[10] = { u[0], u[1], u[1], u[2], u[2],
                                          u[3], u[3], u[4], u[4], u[5] };
                    const float* wk = wc + (kd * 9 + kh * 3) * CO_BLK;
#pragma unroll
                    for (int kw = 0; kw < 3; ++kw) {
#pragma unroll
                        for (int j = 0; j < CO_BLK; ++j) {
                            const float wv = wk[kw * CO_BLK + j];
#pragma unroll
                            for (int o = 0; o < 8; ++o)
                                acc[j][o] = fmaf(v[o + kw], wv, acc[j][o]);
                        }
                    }
                }
            }
        }
    }
#pragma unroll
    for (int j = 0; j < CO_BLK; ++j) {
        T* op = out + (((size_t)(co_base + j) * DD + d0) * Hout + h0) * Wout + w0;
        store8(op, acc[j]);
    }
}

// ---------------------------------------------------------------------------
// fo_pool over D=31. z/f are per-channel [C, D, HW] bases (explicit ptrs).
// out[off] = h_d + a1[off]? + a2[off]?   (a1/a2 nullable). No aliasing used.
// ---------------------------------------------------------------------------
template<typename T, typename TA2, typename TO>
__global__ __launch_bounds__(256)
void fo_pool_k(const T* __restrict__ z, const T* __restrict__ f,
               TO* __restrict__ out, const T* __restrict__ a1,
               const TA2* __restrict__ a2, int C, int HW, int reverse)
{
    const long long idx = (long long)blockIdx.x * 256 + threadIdx.x;
    const int c = (int)(idx / HW);
    if (c >= C) return;
    const int p = (int)(idx - (long long)c * HW);
    const size_t base = (size_t)c * DD * HW + p;
    float h = 0.f;
    if (!reverse) {
        for (int d = 0; d < DD; ++d) {
            const size_t off = base + (size_t)d * HW;
            const float zz = tanhf(toF(z[off]));
            const float ff = sigm(toF(f[off]));
            h = ff * h + (1.f - ff) * zz;
            float v = h;
            if (a1) v += toF(a1[off]);
            if (a2) v += toF(a2[off]);
            stv(out + off, v);
        }
    } else {
        for (int d = DD - 1; d >= 0; --d) {
            const size_t off = base + (size_t)d * HW;
            const float zz = tanhf(toF(z[off]));
            const float ff = sigm(toF(f[off]));
            h = ff * h + (1.f - ff) * zz;
            float v = h;
            if (a1) v += toF(a1[off]);
            if (a2) v += toF(a2[off]);
            stv(out + off, v);
        }
    }
}

// Diagnostic: encode ws_size (MB) into output if workspace too small.
__global__ __launch_bounds__(256)
void diag_k(float* out, float v, int n)
{
    const int i = blockIdx.x * 256 + threadIdx.x;
    if (i < n) out[i] = v;
}

// ---------------------------------------------------------------------------

template<typename TIN, typename T>
static inline void conv_launch(const TIN* in, const float* w, const float* b,
                               T* out, int Cin, int co0, int nCo,
                               int Hin, int Win, int Hout, int Wout,
                               int stride, bool flip, hipStream_t s)
{
    const unsigned gx = (unsigned)((DD * (long long)Hout * Wout) / 2048);
    const float* wp = w + (size_t)co0 * Cin * 27;
    const float* bp = b + co0;
    const int cic = (Cin < CI_CHUNK) ? Cin : CI_CHUNK;
    if (stride == 2) {
        if (nCo % 8 == 0) {
            dim3 grid(gx, nCo / 8);
            conv3d_k<TIN, T, 2, false, 8><<<grid, 256, (size_t)cic * 27 * 8 * 4, s>>>(
                in, wp, bp, out, Cin, Hin, Win, Hout, Wout);
        } else {
            dim3 grid(gx, nCo / 4);
            conv3d_k<TIN, T, 2, false, 4><<<grid, 256, (size_t)cic * 27 * 4 * 4, s>>>(
                in, wp, bp, out, Cin, Hin, Win, Hout, Wout);
        }
    } else if (flip) {
        if (nCo % 8 == 0) {
            dim3 grid(gx, nCo / 8);
            conv3d_k<TIN, T, 1, true, 8><<<grid, 256, (size_t)cic * 27 * 8 * 4, s>>>(
                in, wp, bp, out, Cin, Hin, Win, Hout, Wout);
        } else if (nCo % 4 == 0) {
            dim3 grid(gx, nCo / 4);
            conv3d_k<TIN, T, 1, true, 4><<<grid, 256, (size_t)cic * 27 * 4 * 4, s>>>(
                in, wp, bp, out, Cin, Hin, Win, Hout, Wout);
        } else {  // rec layer: nCo == 3
            dim3 grid(gx, nCo / 3);
            conv3d_k<TIN, T, 1, true, 3><<<grid, 256, (size_t)cic * 27 * 3 * 4, s>>>(
                in, wp, bp, out, Cin, Hin, Win, Hout, Wout);
        }
    } else {
        if (nCo % 8 == 0) {
            dim3 grid(gx, nCo / 8);
            conv3d_k<TIN, T, 1, false, 8><<<grid, 256, (size_t)cic * 27 * 8 * 4, s>>>(
                in, wp, bp, out, Cin, Hin, Win, Hout, Wout);
        } else {
            dim3 grid(gx, nCo / 4);
            conv3d_k<TIN, T, 1, false, 4><<<grid, 256, (size_t)cic * 27 * 4 * 4, s>>>(
                in, wp, bp, out, Cin, Hin, Win, Hout, Wout);
        }
    }
}

template<typename T>
static inline void conv_up_launch(const T* ia, const T* ib, const float* w,
                                  const float* b, T* out, int Cin, int co0,
                                  int nCo, int Hlo, int Wlo, hipStream_t s)
{
    const unsigned gx = (unsigned)((DD * 4LL * Hlo * Wlo) / 2048);
    const int cic = (Cin < CI_CHUNK) ? Cin : CI_CHUNK;
    if (nCo % 8 == 0) {
        dim3 grid(gx, nCo / 8);
        conv3d_up_k<T, 8><<<grid, 256, (size_t)cic * 27 * 8 * 4, s>>>(
            ia, ib, w + (size_t)co0 * Cin * 27, b + co0, out, Cin, Hlo, Wlo);
    } else {
        dim3 grid(gx, nCo / 4);
        conv3d_up_k<T, 4><<<grid, 256, (size_t)cic * 27 * 4 * 4, s>>>(
            ia, ib, w + (size_t)co0 * Cin * 27, b + co0, out, Cin, Hlo, Wlo);
    }
}

template<typename T, typename TA2, typename TO>
static inline void pool_launch(const T* z, const T* f, TO* o, const T* a1,
                               const TA2* a2, int C, int HW, int rev,
                               hipStream_t s)
{
    const long long tot = (long long)C * HW;
    fo_pool_k<T, TA2, TO><<<(unsigned)((tot + 255) / 256), 256, 0, s>>>(
        z, f, o, a1, a2, C, HW, rev);
}

// ---------------------------------------------------------------------------
// Memory plan (units of U). Pool = 56 U. Identical to the passing plan.
// ---------------------------------------------------------------------------
template<typename T>
static void run_net(const float* x, const float* const* W, const float* const* B,
                    float* out, T* P, hipStream_t s)
{
    const T* np = nullptr;
    const T* np2 = nullptr;

    fill_k<T><<<2048, 256, 0, s>>>(P, POOL_UNITS * U);

    T* FE = P + 32 * U;
    // ---- fe = biqrnn(conv(x)) : 1 -> 48 gates -> 16 ch @256, chunks of 4 ---
    for (int a = 0; a < 16; a += 4) {
        conv_launch<float, T>(x, W[0], B[0], P,         1, a,      4, 256, 256, 256, 256, 1, false, s);
        conv_launch<float, T>(x, W[0], B[0], P + 4 * U, 1, 16 + a, 4, 256, 256, 256, 256, 1, false, s);
        conv_launch<float, T>(x, W[0], B[0], P + 8 * U, 1, 32 + a, 4, 256, 256, 256, 256, 1, false, s);
        pool_launch<T, T, T>(P, P + 4 * U, P + 12 * U, np, np2, 4, 65536, 0, s);
        pool_launch<T, T, T>(P, P + 8 * U, FE + (size_t)a * U, P + 12 * U, np2, 4, 65536, 1, s);
    }

    // ---- e0 = qrnn(conv(fe), fwd) : 16 -> 32 -> 16 @256, chunks of 8 -------
    T* E0 = P + 16 * U;
    for (int a = 0; a < 16; a += 8) {
        conv_launch<T, T>(FE, W[1], B[1], P,         16, a,      8, 256, 256, 256, 256, 1, false, s);
        conv_launch<T, T>(FE, W[1], B[1], P + 8 * U, 16, 16 + a, 8, 256, 256, 256, 256, 1, false, s);
        pool_launch<T, T, T>(P, P + 8 * U, E0 + (size_t)a * U, np, np2, 8, 65536, 0, s);
    }
    // FE dead (recomputed later).

    // ---- e1 = qrnn(conv(e0, s2), rev) : 16 -> 64 -> 32 @128 ----------------
    T* E1 = P;
    {
        T* G = P + 32 * U;
        conv_launch<T, T>(E0, W[2], B[2], G, 16, 0, 64, 256, 256, 128, 128, 2, false, s);
        pool_launch<T, T, T>(G, G + 8 * U, E1, np, np2, 32, 16384, 1, s);
    }

    // ---- e2 = qrnn(conv(e1), fwd) : 32 -> 64 -> 32 @128 --------------------
    T* E2 = P + 8 * U;
    {
        T* G = P + 32 * U;
        conv_launch<T, T>(E1, W[3], B[3], G, 32, 0, 64, 128, 128, 128, 128, 1, false, s);
        pool_launch<T, T, T>(G, G + 8 * U, E2, np, np2, 32, 16384, 0, s);
    }

    // ---- e3 = qrnn(conv(e2, s2), rev) : 32 -> 128 -> 64 @64 ----------------
    T* E3 = P + 32 * U;
    {
        T* G = P + 48 * U;
        conv_launch<T, T>(E2, W[4], B[4], G, 32, 0, 128, 128, 128, 64, 64, 2, false, s);
        pool_launch<T, T, T>(G, G + 4 * U, E3, np, np2, 64, 4096, 1, s);
    }

    // ---- e4 = qrnn(conv(e3), fwd) : 64 -> 128 -> 64 @64 --------------------
    T* E4 = P + 40 * U;
    {
        T* G = P + 48 * U;
        conv_launch<T, T>(E3, W[5], B[5], G, 64, 0, 128, 64, 64, 64, 64, 1, false, s);
        pool_launch<T, T, T>(G, G + 4 * U, E4, np, np2, 64, 4096, 0, s);
    }

    // ---- d0 = qrnn(deconv(e4), rev) : 64 -> 128 -> 64 @64 ------------------
    T* D0 = P + 44 * U;
    {
        T* G = P + 48 * U;
        conv_launch<T, T>(E4, W[6], B[6], G, 64, 0, 128, 64, 64, 64, 64, 1, true, s);
        pool_launch<T, T, T>(G, G + 4 * U, D0, np, np2, 64, 4096, 1, s);
    }
    // E4 dead.

    // ---- d1 = qrnn(conv(up(d0+e3)), fwd) + e2 : 64 -> 64 -> 32 @128 --------
    // chunks of 16 out-channels: z 16ch@V2 = 4U, f 4U in G[48,56)
    T* D1 = P + 36 * U;
    for (int a = 0; a < 32; a += 16) {
        T* G = P + 48 * U;
        conv_up_launch<T>(D0, E3, W[7], B[7], G,         64, a,      16, 64, 64, s);
        conv_up_launch<T>(D0, E3, W[7], B[7], G + 4 * U, 64, 32 + a, 16, 64, 64, s);
        pool_launch<T, T, T>(G, G + 4 * U, D1 + (size_t)a * V2,
                             E2 + (size_t)a * V2, np2, 16, 16384, 0, s);
    }
    // E2, E3, D0 dead.

    // ---- d2 = qrnn(deconv(d1), rev) : 32 -> 64 -> 32 @128 ------------------
    T* D2 = P + 8 * U;  // over dead E2
    for (int a = 0; a < 32; a += 16) {
        T* G = P + 48 * U;  // z 16ch@V2=4U, f 4U
        conv_launch<T, T>(D1, W[8], B[8], G,         32, a,      16, 128, 128, 128, 128, 1, true, s);
        conv_launch<T, T>(D1, W[8], B[8], G + 4 * U, 32, 32 + a, 16, 128, 128, 128, 128, 1, true, s);
        pool_launch<T, T, T>(G, G + 4 * U, D2 + (size_t)a * V2, np, np2, 16, 16384, 1, s);
    }
    // D1 dead.

    // ---- d3 = qrnn(conv(up(d2+e1)), fwd) + e0 : 32 -> 32 -> 16 @256 --------
    T* D3 = P + 32 * U;  // fresh 16U
    for (int a = 0; a < 16; a += 4) {
        T* G = P + 48 * U;  // z 4ch@U=4U, f 4U
        conv_up_launch<T>(D2, E1, W[9], B[9], G,         32, a,      4, 128, 128, s);
        conv_up_launch<T>(D2, E1, W[9], B[9], G + 4 * U, 32, 16 + a, 4, 128, 128, s);
        pool_launch<T, T, T>(G, G + 4 * U, D3 + (size_t)a * U,
                             E0 + (size_t)a * U, np2, 4, 65536, 0, s);
    }
    // E0, E1, D2 dead.

    // ---- recompute fe -> FE2 = [0,16), gates at [16,32) --------------------
    T* FE2 = P;
    for (int a = 0; a < 16; a += 4) {
        T* G = P + 16 * U;
        conv_launch<float, T>(x, W[0], B[0], G,         1, a,      4, 256, 256, 256, 256, 1, false, s);
        conv_launch<float, T>(x, W[0], B[0], G + 4 * U, 1, 16 + a, 4, 256, 256, 256, 256, 1, false, s);
        conv_launch<float, T>(x, W[0], B[0], G + 8 * U, 1, 32 + a, 4, 256, 256, 256, 256, 1, false, s);
        pool_launch<T, T, T>(G, G + 4 * U, G + 12 * U, np, np2, 4, 65536, 0, s);
        pool_launch<T, T, T>(G, G + 8 * U, FE2 + (size_t)a * U, G + 12 * U, np2, 4, 65536, 1, s);
    }

    // ---- d4 = qrnn(deconv(d3), rev) + fe : 16 -> 32 -> 16 @256 -------------
    T* D4 = P + 16 * U;  // fresh (over dead FE2-gates region)
    for (int a = 0; a < 16; a += 4) {
        T* G = P + 48 * U;
        conv_launch<T, T>(D3, W[10], B[10], G,         16, a,      4, 256, 256, 256, 256, 1, true, s);
        conv_launch<T, T>(D3, W[10], B[10], G + 4 * U, 16, 16 + a, 4, 256, 256, 256, 256, 1, true, s);
        pool_launch<T, T, T>(G, G + 4 * U, D4 + (size_t)a * U,
                             FE2 + (size_t)a * U, np2, 4, 65536, 1, s);
    }
    // D3, FE2 dead.

    // ---- out = biqrnn(deconv(d4)) + x : 16 -> 3 -> 1 @256 -> fp32 d_out ----
    {
        T* G = P + 32 * U;     // ch0 z, ch1 f1, ch2 f2
        T* TMP = P + 35 * U;
        conv_launch<T, T>(D4, W[11], B[11], G, 16, 0, 3, 256, 256, 256, 256, 1, true, s);
        pool_launch<T, T, T>(G, G + 1 * U, TMP, np, np2, 1, 65536, 0, s);
        pool_launch<T, float, float>(G, G + 2 * U, out, TMP, x, 1, 65536, 1, s);
    }
}

extern "C" void kernel_launch(void* const* d_in, const int* in_sizes, int n_in,
                              void* d_out, int out_size, void* d_ws, size_t ws_size,
                              hipStream_t stream)
{
    const float* x = (const float*)d_in[0];
    const float* W[12];
    const float* B[12];
    for (int i = 0; i < 12; ++i) {
        W[i] = (const float*)d_in[1 + 2 * i];
        B[i] = (const float*)d_in[2 + 2 * i];
    }

    const size_t need_f32 = (size_t)(POOL_UNITS * U) * sizeof(float);  // ~455 MB
    const size_t need_b16 = (size_t)(POOL_UNITS * U) * sizeof(bf16);   // ~227 MB
    if (ws_size >= need_f32) {
        run_net<float>(x, W, B, (float*)d_out, (float*)d_ws, stream);
    } else if (ws_size >= need_b16) {
        run_net<bf16>(x, W, B, (float*)d_out, (bf16*)d_ws, stream);
    } else {
        const float ws_mb = (float)((double)ws_size / 1048576.0);
        diag_k<<<(out_size + 255) / 256, 256, 0, stream>>>(
            (float*)d_out, ws_mb, out_size);
    }
}

// Round 10
// 8216.201 us; speedup vs baseline: 8.3666x; 1.5020x over previous
//
#include <hip/hip_runtime.h>
#include <hip/hip_bf16.h>
#include <cstdint>
#include <cstddef>

using f16 = _Float16;
typedef _Float16 f16x2 __attribute__((ext_vector_type(2)));

static constexpr int DD = 31;                      // depth (time) extent
static constexpr long long U  = 31LL * 256 * 256;  // 2,031,616 elems (1 ch @256)
static constexpr long long V2 = 31LL * 128 * 128;  //   507,904 (1 ch @128)
static constexpr long long V3 = 31LL * 64 * 64;    //   126,976 (1 ch @64)
static constexpr long long POOL_UNITS = 56;        // pool = 56*U f16 elems (~227MB)
static constexpr int CP_CHUNK = 16;                // LDS weight chunk (ci pairs)

union U32H2 { unsigned u; f16x2 h; };

__device__ __forceinline__ float toF(float v) { return v; }
__device__ __forceinline__ float toF(f16 v) { return (float)v; }
__device__ __forceinline__ void stv(float* p, float v) { *p = v; }
__device__ __forceinline__ void stv(f16* p, float v) { *p = (f16)v; }
__device__ __forceinline__ float sigm(float x) { return 1.f / (1.f + __expf(-x)); }

__device__ __forceinline__ unsigned packh2(float a, float b)
{
    U32H2 r; r.h = f16x2{(f16)a, (f16)b}; return r.u;
}
__device__ __forceinline__ unsigned addh2(unsigned a, unsigned b)
{
    U32H2 x, y, r; x.u = a; y.u = b; r.h = x.h + y.h; return r.u;
}
__device__ __forceinline__ float dot2f(unsigned v, unsigned w, float c)
{
#if __has_builtin(__builtin_amdgcn_fdot2)
    U32H2 uv, uw; uv.u = v; uw.u = w;
    return __builtin_amdgcn_fdot2(uv.h, uw.h, c, false);
#else
    U32H2 uv, uw; uv.u = v; uw.u = w;
    c = fmaf((float)uv.h.x, (float)uw.h.x, c);
    return fmaf((float)uv.h.y, (float)uw.h.y, c);
#endif
}

// ---------------------------------------------------------------------------
__global__ __launch_bounds__(256)
void fill_k(f16* p, long long n)
{
    const long long stride = (long long)gridDim.x * 256;
    for (long long i = (long long)blockIdx.x * 256 + threadIdx.x; i < n; i += stride)
        p[i] = (f16)0.f;
}

// ---------------------------------------------------------------------------
// Pair-interleaved direct conv3d, 3x3x3, pad 1. Input/output layout
// [C/2][D][H][W][2] f16 (one dword = 1 position x 2 channels). W-tile 8.
// Inner op: V_DOT2_F32_F16 -> 2 MACs/instr, fp32 accumulate. Weights staged
// in LDS as packed (ci,ci+1) pairs, [cp*27+k][CO_BLK], FLIP at staging.
// OUT_IL=false writes plain [nCo][D][H][W] (rec layer).
// Requires DD*Hout*Wout % 2048 == 0, Wout % 8 == 0, Cin even, co_base even.
// ---------------------------------------------------------------------------
template<int STRIDE, bool FLIP, int CO_BLK, bool OUT_IL>
__global__ __launch_bounds__(256)
void conv3d_il_k(const f16* __restrict__ in, const float* __restrict__ wt,
                 const float* __restrict__ bias, f16* __restrict__ out,
                 int Cin, int Hin, int Win, int Hout, int Wout)
{
    extern __shared__ unsigned wl2[];  // [CP_CHUNK*27][CO_BLK]
    const int co_base = blockIdx.y * CO_BLK;

    const int s8 = (blockIdx.x * 256 + threadIdx.x) * 8;
    const int w0 = s8 % Wout;
    const int sh = s8 / Wout;
    const int h0 = sh % Hout;
    const int d0 = sh / Hout;

    float acc[CO_BLK][8];
#pragma unroll
    for (int j = 0; j < CO_BLK; ++j) {
        const float bv = bias[co_base + j];
#pragma unroll
        for (int o = 0; o < 8; ++o) acc[j][o] = bv;
    }

    const size_t HWin = (size_t)Hin * Win;
    const int CP = Cin >> 1;

    for (int cp0 = 0; cp0 < CP; cp0 += CP_CHUNK) {
        const int cnp = (CP - cp0 < CP_CHUNK) ? (CP - cp0) : CP_CHUNK;
        __syncthreads();
        for (int t = threadIdx.x; t < cnp * 27 * CO_BLK; t += 256) {
            const int j = t % CO_BLK;
            const int k = (t / CO_BLK) % 27;
            const int cp = t / (CO_BLK * 27);
            int src;
            if (FLIP) {
                const int kd = k / 9, kh = (k / 3) % 3, kw = k % 3;
                src = (2 - kd) * 9 + (2 - kh) * 3 + (2 - kw);
            } else {
                src = k;
            }
            const int ci = (cp0 + cp) * 2;
            const size_t wb = (size_t)(co_base + j) * Cin;
            wl2[t] = packh2(wt[(wb + ci) * 27 + src], wt[(wb + ci + 1) * 27 + src]);
        }
        __syncthreads();

        for (int cp = 0; cp < cnp; ++cp) {
            const f16* cb = in + (size_t)(cp0 + cp) * DD * HWin * 2;
            const unsigned* wc = wl2 + cp * 27 * CO_BLK;
#pragma unroll
            for (int kd = 0; kd < 3; ++kd) {
                const int di = d0 + kd - 1;
                if (di < 0 || di >= DD) continue;
#pragma unroll
                for (int kh = 0; kh < 3; ++kh) {
                    const int hi = h0 * STRIDE + kh - 1;
                    if (hi < 0 || hi >= Hin) continue;
                    const unsigned* rowu = (const unsigned*)
                        (cb + ((size_t)di * HWin + (size_t)hi * Win) * 2);
                    if (STRIDE == 1) {
                        unsigned v2[10];
                        v2[0] = (w0 > 0) ? rowu[w0 - 1] : 0u;
                        const uint4 q1 = *(const uint4*)(rowu + w0);
                        const uint4 q2 = *(const uint4*)(rowu + w0 + 4);
                        v2[1] = q1.x; v2[2] = q1.y; v2[3] = q1.z; v2[4] = q1.w;
                        v2[5] = q2.x; v2[6] = q2.y; v2[7] = q2.z; v2[8] = q2.w;
                        v2[9] = (w0 + 8 < Win) ? rowu[w0 + 8] : 0u;
                        const unsigned* wk = wc + (kd * 9 + kh * 3) * CO_BLK;
#pragma unroll
                        for (int kw = 0; kw < 3; ++kw) {
#pragma unroll
                            for (int j = 0; j < CO_BLK; ++j) {
                                const unsigned wv = wk[kw * CO_BLK + j];
#pragma unroll
                                for (int o = 0; o < 8; ++o)
                                    acc[j][o] = dot2f(v2[o + kw], wv, acc[j][o]);
                            }
                        }
                    } else {
                        unsigned v2[17];
                        const int p0 = w0 * 2;
                        v2[0] = (w0 > 0) ? rowu[p0 - 1] : 0u;
#pragma unroll
                        for (int q = 0; q < 4; ++q) {
                            const uint4 qq = *(const uint4*)(rowu + p0 + 4 * q);
                            v2[1 + 4 * q] = qq.x; v2[2 + 4 * q] = qq.y;
                            v2[3 + 4 * q] = qq.z; v2[4 + 4 * q] = qq.w;
                        }
                        const unsigned* wk = wc + (kd * 9 + kh * 3) * CO_BLK;
#pragma unroll
                        for (int kw = 0; kw < 3; ++kw) {
#pragma unroll
                            for (int j = 0; j < CO_BLK; ++j) {
                                const unsigned wv = wk[kw * CO_BLK + j];
#pragma unroll
                                for (int o = 0; o < 8; ++o)
                                    acc[j][o] = dot2f(v2[2 * o + kw], wv, acc[j][o]);
                            }
                        }
                    }
                }
            }
        }
    }

    if (OUT_IL) {
#pragma unroll
        for (int pj = 0; pj < CO_BLK / 2; ++pj) {
            f16* op = out + ((((size_t)((co_base >> 1) + pj) * DD + d0) * Hout + h0)
                             * Wout + w0) * 2;
            unsigned dw[8];
#pragma unroll
            for (int o = 0; o < 8; ++o)
                dw[o] = packh2(acc[2 * pj][o], acc[2 * pj + 1][o]);
            *(uint4*)op = make_uint4(dw[0], dw[1], dw[2], dw[3]);
            *(uint4*)(op + 8) = make_uint4(dw[4], dw[5], dw[6], dw[7]);
        }
    } else {
#pragma unroll
        for (int j = 0; j < CO_BLK; ++j) {
            f16* op = out + (((size_t)(co_base + j) * DD + d0) * Hout + h0) * Wout + w0;
            unsigned dw[4];
#pragma unroll
            for (int o = 0; o < 4; ++o)
                dw[o] = packh2(acc[j][2 * o], acc[j][2 * o + 1]);
            *(uint4*)op = make_uint4(dw[0], dw[1], dw[2], dw[3]);
        }
    }
}

// ---------------------------------------------------------------------------
// Fused conv3d( upsample2x(a + b) ), stride 1, no flip, pair-interleaved.
// ---------------------------------------------------------------------------
template<int CO_BLK>
__global__ __launch_bounds__(256)
void conv3d_up_il_k(const f16* __restrict__ ia, const f16* __restrict__ ib,
                    const float* __restrict__ wt, const float* __restrict__ bias,
                    f16* __restrict__ out, int Cin, int Hlo, int Wlo)
{
    extern __shared__ unsigned wl2[];
    const int co_base = blockIdx.y * CO_BLK;

    const int Hout = 2 * Hlo, Wout = 2 * Wlo;
    const int s8 = (blockIdx.x * 256 + threadIdx.x) * 8;
    const int w0 = s8 % Wout;
    const int sh = s8 / Wout;
    const int h0 = sh % Hout;
    const int d0 = sh / Hout;
    const int lw = w0 >> 1;  // multiple of 4

    float acc[CO_BLK][8];
#pragma unroll
    for (int j = 0; j < CO_BLK; ++j) {
        const float bv = bias[co_base + j];
#pragma unroll
        for (int o = 0; o < 8; ++o) acc[j][o] = bv;
    }
    const size_t HWlo = (size_t)Hlo * Wlo;
    const int CP = Cin >> 1;

    for (int cp0 = 0; cp0 < CP; cp0 += CP_CHUNK) {
        const int cnp = (CP - cp0 < CP_CHUNK) ? (CP - cp0) : CP_CHUNK;
        __syncthreads();
        for (int t = threadIdx.x; t < cnp * 27 * CO_BLK; t += 256) {
            const int j = t % CO_BLK;
            const int k = (t / CO_BLK) % 27;
            const int cp = t / (CO_BLK * 27);
            const int ci = (cp0 + cp) * 2;
            const size_t wb = (size_t)(co_base + j) * Cin;
            wl2[t] = packh2(wt[(wb + ci) * 27 + k], wt[(wb + ci + 1) * 27 + k]);
        }
        __syncthreads();

        for (int cp = 0; cp < cnp; ++cp) {
            const f16* cba = ia + (size_t)(cp0 + cp) * DD * HWlo * 2;
            const f16* cbb = ib + (size_t)(cp0 + cp) * DD * HWlo * 2;
            const unsigned* wc = wl2 + cp * 27 * CO_BLK;
#pragma unroll
            for (int kd = 0; kd < 3; ++kd) {
                const int di = d0 + kd - 1;
                if (di < 0 || di >= DD) continue;
#pragma unroll
                for (int kh = 0; kh < 3; ++kh) {
                    const int hi = h0 + kh - 1;
                    if (hi < 0 || hi >= Hout) continue;
                    const int hlo = hi >> 1;
                    const unsigned* rua = (const unsigned*)
                        (cba + ((size_t)di * HWlo + (size_t)hlo * Wlo) * 2);
                    const unsigned* rub = (const unsigned*)
                        (cbb + ((size_t)di * HWlo + (size_t)hlo * Wlo) * 2);
                    unsigned u[6];
                    u[0] = (lw > 0) ? addh2(rua[lw - 1], rub[lw - 1]) : 0u;
                    const uint4 qa = *(const uint4*)(rua + lw);
                    const uint4 qb = *(const uint4*)(rub + lw);
                    u[1] = addh2(qa.x, qb.x); u[2] = addh2(qa.y, qb.y);
                    u[3] = addh2(qa.z, qb.z); u[4] = addh2(qa.w, qb.w);
                    u[5] = (lw + 4 < Wlo) ? addh2(rua[lw + 4], rub[lw + 4]) : 0u;
                    // upsampled window: up-w = w0-1+t, t in [0,10)
                    const unsigned v2[10] = { u[0], u[1], u[1], u[2], u[2],
                                              u[3], u[3], u[4], u[4], u[5] };
                    const unsigned* wk = wc + (kd * 9 + kh * 3) * CO_BLK;
#pragma unroll
                    for (int kw = 0; kw < 3; ++kw) {
#pragma unroll
                        for (int j = 0; j < CO_BLK; ++j) {
                            const unsigned wv = wk[kw * CO_BLK + j];
#pragma unroll
                            for (int o = 0; o < 8; ++o)
                                acc[j][o] = dot2f(v2[o + kw], wv, acc[j][o]);
                        }
                    }
                }
            }
        }
    }
#pragma unroll
    for (int pj = 0; pj < CO_BLK / 2; ++pj) {
        f16* op = out + ((((size_t)((co_base >> 1) + pj) * DD + d0) * Hout + h0)
                         * Wout + w0) * 2;
        unsigned dw[8];
#pragma unroll
        for (int o = 0; o < 8; ++o)
            dw[o] = packh2(acc[2 * pj][o], acc[2 * pj + 1][o]);
        *(uint4*)op = make_uint4(dw[0], dw[1], dw[2], dw[3]);
        *(uint4*)(op + 8) = make_uint4(dw[4], dw[5], dw[6], dw[7]);
    }
}

// ---------------------------------------------------------------------------
// fe conv: Cin=1, fp32 plain input x, interleaved f16 out (CO_BLK=4). @256^2.
// ---------------------------------------------------------------------------
__global__ __launch_bounds__(256)
void conv_fe_k(const float* __restrict__ in, const float* __restrict__ wt,
               const float* __restrict__ bias, f16* __restrict__ out)
{
    __shared__ float wl[27 * 4];
    for (int t = threadIdx.x; t < 27 * 4; t += 256) {
        const int j = t % 4;
        const int k = t / 4;
        wl[t] = wt[(size_t)j * 27 + k];
    }
    __syncthreads();

    const int W = 256, H = 256;
    const int s8 = (blockIdx.x * 256 + threadIdx.x) * 8;
    const int w0 = s8 % W;
    const int sh = s8 / W;
    const int h0 = sh % H;
    const int d0 = sh / H;

    float acc[4][8];
#pragma unroll
    for (int j = 0; j < 4; ++j) {
        const float bv = bias[j];
#pragma unroll
        for (int o = 0; o < 8; ++o) acc[j][o] = bv;
    }
    const size_t HW = 65536;

#pragma unroll
    for (int kd = 0; kd < 3; ++kd) {
        const int di = d0 + kd - 1;
        if (di < 0 || di >= DD) continue;
#pragma unroll
        for (int kh = 0; kh < 3; ++kh) {
            const int hi = h0 + kh - 1;
            if (hi < 0 || hi >= H) continue;
            const float* row = in + (size_t)di * HW + (size_t)hi * W + w0;
            float v[10];
            v[0] = (w0 > 0) ? row[-1] : 0.f;
            const float4 q1 = *(const float4*)row;
            const float4 q2 = *(const float4*)(row + 4);
            v[1] = q1.x; v[2] = q1.y; v[3] = q1.z; v[4] = q1.w;
            v[5] = q2.x; v[6] = q2.y; v[7] = q2.z; v[8] = q2.w;
            v[9] = (w0 + 8 < W) ? row[8] : 0.f;
            const float* wk = wl + (kd * 9 + kh * 3) * 4;
#pragma unroll
            for (int kw = 0; kw < 3; ++kw) {
#pragma unroll
                for (int j = 0; j < 4; ++j) {
                    const float wv = wk[kw * 4 + j];
#pragma unroll
                    for (int o = 0; o < 8; ++o)
                        acc[j][o] = fmaf(v[o + kw], wv, acc[j][o]);
                }
            }
        }
    }
#pragma unroll
    for (int pj = 0; pj < 2; ++pj) {
        f16* op = out + (((size_t)pj * DD + d0) * H + h0) * (size_t)W * 2 + (size_t)w0 * 2;
        unsigned dw[8];
#pragma unroll
        for (int o = 0; o < 8; ++o)
            dw[o] = packh2(acc[2 * pj][o], acc[2 * pj + 1][o]);
        *(uint4*)op = make_uint4(dw[0], dw[1], dw[2], dw[3]);
        *(uint4*)(op + 8) = make_uint4(dw[4], dw[5], dw[6], dw[7]);
    }
}

// ---------------------------------------------------------------------------
// fo_pool over D=31. IL=true: pair-interleaved [C/2][D][HW][2]; else plain
// [C][D][HW]. z/f/a1 share the layout; a2 (x, fp32) plain-only.
// out = h_d + a1? + a2?
// ---------------------------------------------------------------------------
template<bool IL, typename TA1, typename TA2, typename TO>
__global__ __launch_bounds__(256)
void fo_pool_k(const f16* __restrict__ z, const f16* __restrict__ f,
               TO* __restrict__ out, const TA1* __restrict__ a1,
               const TA2* __restrict__ a2, int C, int HW, int reverse)
{
    const long long idx = (long long)blockIdx.x * 256 + threadIdx.x;
    if (idx >= (long long)C * HW) return;
    size_t base; size_t step;
    if (IL) {
        const long long pairIdx = idx / (2LL * HW);
        const int rem = (int)(idx - pairIdx * 2LL * HW);
        const int p = rem >> 1;
        const int par = rem & 1;
        base = ((size_t)pairIdx * DD * HW + p) * 2 + par;
        step = (size_t)HW * 2;
    } else {
        const int c = (int)(idx / HW);
        const int p = (int)(idx - (long long)c * HW);
        base = (size_t)c * DD * HW + p;
        step = (size_t)HW;
    }
    float h = 0.f;
    if (!reverse) {
        for (int d = 0; d < DD; ++d) {
            const size_t off = base + (size_t)d * step;
            const float zz = tanhf(toF(z[off]));
            const float ff = sigm(toF(f[off]));
            h = ff * h + (1.f - ff) * zz;
            float v = h;
            if (a1) v += toF(a1[off]);
            if (a2) v += toF(a2[off]);
            stv(out + off, v);
        }
    } else {
        for (int d = DD - 1; d >= 0; --d) {
            const size_t off = base + (size_t)d * step;
            const float zz = tanhf(toF(z[off]));
            const float ff = sigm(toF(f[off]));
            h = ff * h + (1.f - ff) * zz;
            float v = h;
            if (a1) v += toF(a1[off]);
            if (a2) v += toF(a2[off]);
            stv(out + off, v);
        }
    }
}

// Diagnostic: encode ws_size (MB) into output if workspace too small.
__global__ __launch_bounds__(256)
void diag_k(float* out, float v, int n)
{
    const int i = blockIdx.x * 256 + threadIdx.x;
    if (i < n) out[i] = v;
}

// ---------------------------------------------------------------------------

static inline void conv_launch(const f16* in, const float* w, const float* b,
                               f16* out, int Cin, int co0, int nCo,
                               int Hin, int Win, int Hout, int Wout,
                               int stride, bool flip, hipStream_t s)
{
    const unsigned gx = (unsigned)((DD * (long long)Hout * Wout) / 2048);
    const float* wp = w + (size_t)co0 * Cin * 27;
    const float* bp = b + co0;
    const int cpc = (Cin / 2 < CP_CHUNK) ? Cin / 2 : CP_CHUNK;
    if (stride == 2) {
        dim3 grid(gx, nCo / 8);
        conv3d_il_k<2, false, 8, true><<<grid, 256, (size_t)cpc * 27 * 8 * 4, s>>>(
            in, wp, bp, out, Cin, Hin, Win, Hout, Wout);
    } else if (flip) {
        if (nCo % 8 == 0) {
            dim3 grid(gx, nCo / 8);
            conv3d_il_k<1, true, 8, true><<<grid, 256, (size_t)cpc * 27 * 8 * 4, s>>>(
                in, wp, bp, out, Cin, Hin, Win, Hout, Wout);
        } else if (nCo % 4 == 0) {
            dim3 grid(gx, nCo / 4);
            conv3d_il_k<1, true, 4, true><<<grid, 256, (size_t)cpc * 27 * 4 * 4, s>>>(
                in, wp, bp, out, Cin, Hin, Win, Hout, Wout);
        } else {  // rec layer: nCo == 3, plain output
            dim3 grid(gx, 1);
            conv3d_il_k<1, true, 3, false><<<grid, 256, (size_t)cpc * 27 * 3 * 4, s>>>(
                in, wp, bp, out, Cin, Hin, Win, Hout, Wout);
        }
    } else {
        if (nCo % 8 == 0) {
            dim3 grid(gx, nCo / 8);
            conv3d_il_k<1, false, 8, true><<<grid, 256, (size_t)cpc * 27 * 8 * 4, s>>>(
                in, wp, bp, out, Cin, Hin, Win, Hout, Wout);
        } else {
            dim3 grid(gx, nCo / 4);
            conv3d_il_k<1, false, 4, true><<<grid, 256, (size_t)cpc * 27 * 4 * 4, s>>>(
                in, wp, bp, out, Cin, Hin, Win, Hout, Wout);
        }
    }
}

static inline void conv_up_launch(const f16* ia, const f16* ib, const float* w,
                                  const float* b, f16* out, int Cin, int co0,
                                  int nCo, int Hlo, int Wlo, hipStream_t s)
{
    const unsigned gx = (unsigned)((DD * 4LL * Hlo * Wlo) / 2048);
    const int cpc = (Cin / 2 < CP_CHUNK) ? Cin / 2 : CP_CHUNK;
    if (nCo % 8 == 0) {
        dim3 grid(gx, nCo / 8);
        conv3d_up_il_k<8><<<grid, 256, (size_t)cpc * 27 * 8 * 4, s>>>(
            ia, ib, w + (size_t)co0 * Cin * 27, b + co0, out, Cin, Hlo, Wlo);
    } else {
        dim3 grid(gx, nCo / 4);
        conv3d_up_il_k<4><<<grid, 256, (size_t)cpc * 27 * 4 * 4, s>>>(
            ia, ib, w + (size_t)co0 * Cin * 27, b + co0, out, Cin, Hlo, Wlo);
    }
}

template<bool IL, typename TA1, typename TA2, typename TO>
static inline void pool_launch(const f16* z, const f16* f, TO* o, const TA1* a1,
                               const TA2* a2, int C, int HW, int rev,
                               hipStream_t s)
{
    const long long tot = (long long)C * HW;
    fo_pool_k<IL, TA1, TA2, TO><<<(unsigned)((tot + 255) / 256), 256, 0, s>>>(
        z, f, o, a1, a2, C, HW, rev);
}

// ---------------------------------------------------------------------------
// Memory plan (units of U). Pool = 56 U f16. Same slot plan as rounds 6-9;
// all base shifts are whole channel-pairs, so interleaving is transparent.
// ---------------------------------------------------------------------------
static void run_net(const float* x, const float* const* W, const float* const* B,
                    float* out, f16* P, hipStream_t s)
{
    const f16* np = nullptr;
    const float* npf = nullptr;

    fill_k<<<2048, 256, 0, s>>>(P, POOL_UNITS * U);

    f16* FE = P + 32 * U;
    // ---- fe = biqrnn(conv(x)) : 1 -> 48 gates -> 16 ch @256, chunks of 4 ---
    for (int a = 0; a < 16; a += 4) {
        conv_fe_k<<<992, 256, 0, s>>>(x, W[0] + (size_t)a * 27,        B[0] + a,      P);
        conv_fe_k<<<992, 256, 0, s>>>(x, W[0] + (size_t)(16 + a) * 27, B[0] + 16 + a, P + 4 * U);
        conv_fe_k<<<992, 256, 0, s>>>(x, W[0] + (size_t)(32 + a) * 27, B[0] + 32 + a, P + 8 * U);
        pool_launch<true, f16, float, f16>(P, P + 4 * U, P + 12 * U, np, npf, 4, 65536, 0, s);
        pool_launch<true, f16, float, f16>(P, P + 8 * U, FE + (size_t)a * U, P + 12 * U, npf, 4, 65536, 1, s);
    }

    // ---- e0 = qrnn(conv(fe), fwd) : 16 -> 32 -> 16 @256, chunks of 8 -------
    f16* E0 = P + 16 * U;
    for (int a = 0; a < 16; a += 8) {
        conv_launch(FE, W[1], B[1], P,         16, a,      8, 256, 256, 256, 256, 1, false, s);
        conv_launch(FE, W[1], B[1], P + 8 * U, 16, 16 + a, 8, 256, 256, 256, 256, 1, false, s);
        pool_launch<true, f16, float, f16>(P, P + 8 * U, E0 + (size_t)a * U, np, npf, 8, 65536, 0, s);
    }
    // FE dead (recomputed later).

    // ---- e1 = qrnn(conv(e0, s2), rev) : 16 -> 64 -> 32 @128 ----------------
    f16* E1 = P;
    {
        f16* G = P + 32 * U;
        conv_launch(E0, W[2], B[2], G, 16, 0, 64, 256, 256, 128, 128, 2, false, s);
        pool_launch<true, f16, float, f16>(G, G + 8 * U, E1, np, npf, 32, 16384, 1, s);
    }

    // ---- e2 = qrnn(conv(e1), fwd) : 32 -> 64 -> 32 @128 --------------------
    f16* E2 = P + 8 * U;
    {
        f16* G = P + 32 * U;
        conv_launch(E1, W[3], B[3], G, 32, 0, 64, 128, 128, 128, 128, 1, false, s);
        pool_launch<true, f16, float, f16>(G, G + 8 * U, E2, np, npf, 32, 16384, 0, s);
    }

    // ---- e3 = qrnn(conv(e2, s2), rev) : 32 -> 128 -> 64 @64 ----------------
    f16* E3 = P + 32 * U;
    {
        f16* G = P + 48 * U;
        conv_launch(E2, W[4], B[4], G, 32, 0, 128, 128, 128, 64, 64, 2, false, s);
        pool_launch<true, f16, float, f16>(G, G + 4 * U, E3, np, npf, 64, 4096, 1, s);
    }

    // ---- e4 = qrnn(conv(e3), fwd) : 64 -> 128 -> 64 @64 --------------------
    f16* E4 = P + 40 * U;
    {
        f16* G = P + 48 * U;
        conv_launch(E3, W[5], B[5], G, 64, 0, 128, 64, 64, 64, 64, 1, false, s);
        pool_launch<true, f16, float, f16>(G, G + 4 * U, E4, np, npf, 64, 4096, 0, s);
    }

    // ---- d0 = qrnn(deconv(e4), rev) : 64 -> 128 -> 64 @64 ------------------
    f16* D0 = P + 44 * U;
    {
        f16* G = P + 48 * U;
        conv_launch(E4, W[6], B[6], G, 64, 0, 128, 64, 64, 64, 64, 1, true, s);
        pool_launch<true, f16, float, f16>(G, G + 4 * U, D0, np, npf, 64, 4096, 1, s);
    }
    // E4 dead.

    // ---- d1 = qrnn(conv(up(d0+e3)), fwd) + e2 : 64 -> 64 -> 32 @128 --------
    f16* D1 = P + 36 * U;
    for (int a = 0; a < 32; a += 16) {
        f16* G = P + 48 * U;  // z 16ch@V2 = 4U, f 4U
        conv_up_launch(D0, E3, W[7], B[7], G,         64, a,      16, 64, 64, s);
        conv_up_launch(D0, E3, W[7], B[7], G + 4 * U, 64, 32 + a, 16, 64, 64, s);
        pool_launch<true, f16, float, f16>(G, G + 4 * U, D1 + (size_t)a * V2,
                                           E2 + (size_t)a * V2, npf, 16, 16384, 0, s);
    }
    // E2, E3, D0 dead.

    // ---- d2 = qrnn(deconv(d1), rev) : 32 -> 64 -> 32 @128 ------------------
    f16* D2 = P + 8 * U;  // over dead E2
    for (int a = 0; a < 32; a += 16) {
        f16* G = P + 48 * U;
        conv_launch(D1, W[8], B[8], G,         32, a,      16, 128, 128, 128, 128, 1, true, s);
        conv_launch(D1, W[8], B[8], G + 4 * U, 32, 32 + a, 16, 128, 128, 128, 128, 1, true, s);
        pool_launch<true, f16, float, f16>(G, G + 4 * U, D2 + (size_t)a * V2, np, npf, 16, 16384, 1, s);
    }
    // D1 dead.

    // ---- d3 = qrnn(conv(up(d2+e1)), fwd) + e0 : 32 -> 32 -> 16 @256 --------
    f16* D3 = P + 32 * U;  // fresh 16U
    for (int a = 0; a < 16; a += 4) {
        f16* G = P + 48 * U;  // z 4ch@U=4U, f 4U
        conv_up_launch(D2, E1, W[9], B[9], G,         32, a,      4, 128, 128, s);
        conv_up_launch(D2, E1, W[9], B[9], G + 4 * U, 32, 16 + a, 4, 128, 128, s);
        pool_launch<true, f16, float, f16>(G, G + 4 * U, D3 + (size_t)a * U,
                                           E0 + (size_t)a * U, npf, 4, 65536, 0, s);
    }
    // E0, E1, D2 dead.

    // ---- recompute fe -> FE2 = [0,16), gates at [16,32) --------------------
    f16* FE2 = P;
    for (int a = 0; a < 16; a += 4) {
        f16* G = P + 16 * U;
        conv_fe_k<<<992, 256, 0, s>>>(x, W[0] + (size_t)a * 27,        B[0] + a,      G);
        conv_fe_k<<<992, 256, 0, s>>>(x, W[0] + (size_t)(16 + a) * 27, B[0] + 16 + a, G + 4 * U);
        conv_fe_k<<<992, 256, 0, s>>>(x, W[0] + (size_t)(32 + a) * 27, B[0] + 32 + a, G + 8 * U);
        pool_launch<true, f16, float, f16>(G, G + 4 * U, G + 12 * U, np, npf, 4, 65536, 0, s);
        pool_launch<true, f16, float, f16>(G, G + 8 * U, FE2 + (size_t)a * U, G + 12 * U, npf, 4, 65536, 1, s);
    }

    // ---- d4 = qrnn(deconv(d3), rev) + fe : 16 -> 32 -> 16 @256 -------------
    f16* D4 = P + 16 * U;
    for (int a = 0; a < 16; a += 4) {
        f16* G = P + 48 * U;
        conv_launch(D3, W[10], B[10], G,         16, a,      4, 256, 256, 256, 256, 1, true, s);
        conv_launch(D3, W[10], B[10], G + 4 * U, 16, 16 + a, 4, 256, 256, 256, 256, 1, true, s);
        pool_launch<true, f16, float, f16>(G, G + 4 * U, D4 + (size_t)a * U,
                                           FE2 + (size_t)a * U, npf, 4, 65536, 1, s);
    }
    // D3, FE2 dead.

    // ---- out = biqrnn(deconv(d4)) + x : 16 -> 3 -> 1 @256 -> fp32 d_out ----
    {
        f16* G = P + 32 * U;   // plain: ch0 z, ch1 f1, ch2 f2
        f16* TMP = P + 35 * U;
        conv_launch(D4, W[11], B[11], G, 16, 0, 3, 256, 256, 256, 256, 1, true, s);
        pool_launch<false, f16, float, f16>(G, G + 1 * U, TMP, np, npf, 1, 65536, 0, s);
        pool_launch<false, f16, float, float>(G, G + 2 * U, out, TMP, x, 1, 65536, 1, s);
    }
}

extern "C" void kernel_launch(void* const* d_in, const int* in_sizes, int n_in,
                              void* d_out, int out_size, void* d_ws, size_t ws_size,
                              hipStream_t stream)
{
    const float* x = (const float*)d_in[0];
    const float* W[12];
    const float* B[12];
    for (int i = 0; i < 12; ++i) {
        W[i] = (const float*)d_in[1 + 2 * i];
        B[i] = (const float*)d_in[2 + 2 * i];
    }

    const size_t need = (size_t)(POOL_UNITS * U) * sizeof(f16);  // ~227 MB
    if (ws_size >= need) {
        run_net(x, W, B, (float*)d_out, (f16*)d_ws, stream);
    } else {
        const float ws_mb = (float)((double)ws_size / 1048576.0);
        diag_k<<<(out_size + 255) / 256, 256, 0, stream>>>(
            (float*)d_out, ws_mb, out_size);
    }
}

// Round 11
// 8206.468 us; speedup vs baseline: 8.3765x; 1.0012x over previous
//
#include <hip/hip_runtime.h>
#include <hip/hip_bf16.h>
#include <cstdint>
#include <cstddef>

using f16 = _Float16;
typedef _Float16 f16x2 __attribute__((ext_vector_type(2)));

static constexpr int DD = 31;                      // depth (time) extent
static constexpr long long U  = 31LL * 256 * 256;  // 2,031,616 elems (1 ch @256)
static constexpr long long V2 = 31LL * 128 * 128;  //   507,904 (1 ch @128)
static constexpr long long V3 = 31LL * 64 * 64;    //   126,976 (1 ch @64)
static constexpr long long POOL_UNITS = 56;        // pool = 56*U f16 elems (~227MB)
static constexpr int CP_CHUNK = 16;                // LDS weight chunk (ci pairs)

union U32H2 { unsigned u; f16x2 h; };

__device__ __forceinline__ float toF(float v) { return v; }
__device__ __forceinline__ float toF(f16 v) { return (float)v; }
__device__ __forceinline__ void stv(float* p, float v) { *p = v; }
__device__ __forceinline__ void stv(f16* p, float v) { *p = (f16)v; }
__device__ __forceinline__ float sigm(float x) { return 1.f / (1.f + __expf(-x)); }

__device__ __forceinline__ unsigned packh2(float a, float b)
{
    U32H2 r; r.h = f16x2{(f16)a, (f16)b}; return r.u;
}
__device__ __forceinline__ unsigned addh2(unsigned a, unsigned b)
{
    U32H2 x, y, r; x.u = a; y.u = b; r.h = x.h + y.h; return r.u;
}
__device__ __forceinline__ float dot2f(unsigned v, unsigned w, float c)
{
#if __has_builtin(__builtin_amdgcn_fdot2)
    U32H2 uv, uw; uv.u = v; uw.u = w;
    return __builtin_amdgcn_fdot2(uv.h, uw.h, c, false);
#else
    U32H2 uv, uw; uv.u = v; uw.u = w;
    c = fmaf((float)uv.h.x, (float)uw.h.x, c);
    return fmaf((float)uv.h.y, (float)uw.h.y, c);
#endif
}

// ---------------------------------------------------------------------------
__global__ __launch_bounds__(256)
void fill_k(f16* p, long long n)
{
    const long long stride = (long long)gridDim.x * 256;
    for (long long i = (long long)blockIdx.x * 256 + threadIdx.x; i < n; i += stride)
        p[i] = (f16)0.f;
}

// ---------------------------------------------------------------------------
// Pair-interleaved direct conv3d, 3x3x3, pad 1. Input/output layout
// [C/2][D][H][W][2] f16 (one dword = 1 position x 2 channels). W-tile 8.
// Inner op: V_DOT2_F32_F16 -> 2 MACs/instr, fp32 accumulate. Weights staged
// in LDS as packed (ci,ci+1) pairs, [cp*27+k][CO_BLK], FLIP at staging.
// __launch_bounds__(256,2): 2 waves/SIMD min -> 256 VGPR budget, so the
// acc[CO_BLK][8] working set (64 fp32) stays in registers (round-10 ran at
// VGPR=60 -> accumulator spill to scratch, 9x VALU amplification).
// OUT_IL=false writes plain [nCo][D][H][W] (rec layer).
// Requires DD*Hout*Wout % 2048 == 0, Wout % 8 == 0, Cin even, co_base even.
// ---------------------------------------------------------------------------
template<int STRIDE, bool FLIP, int CO_BLK, bool OUT_IL>
__global__ __launch_bounds__(256, 2)
void conv3d_il_k(const f16* __restrict__ in, const float* __restrict__ wt,
                 const float* __restrict__ bias, f16* __restrict__ out,
                 int Cin, int Hin, int Win, int Hout, int Wout)
{
    extern __shared__ unsigned wl2[];  // [CP_CHUNK*27][CO_BLK]
    const int co_base = blockIdx.y * CO_BLK;

    const int s8 = (blockIdx.x * 256 + threadIdx.x) * 8;
    const int w0 = s8 % Wout;
    const int sh = s8 / Wout;
    const int h0 = sh % Hout;
    const int d0 = sh / Hout;

    float acc[CO_BLK][8];
#pragma unroll
    for (int j = 0; j < CO_BLK; ++j) {
        const float bv = bias[co_base + j];
#pragma unroll
        for (int o = 0; o < 8; ++o) acc[j][o] = bv;
    }

    const size_t HWin = (size_t)Hin * Win;
    const int CP = Cin >> 1;

    for (int cp0 = 0; cp0 < CP; cp0 += CP_CHUNK) {
        const int cnp = (CP - cp0 < CP_CHUNK) ? (CP - cp0) : CP_CHUNK;
        __syncthreads();
        for (int t = threadIdx.x; t < cnp * 27 * CO_BLK; t += 256) {
            const int j = t % CO_BLK;
            const int k = (t / CO_BLK) % 27;
            const int cp = t / (CO_BLK * 27);
            int src;
            if (FLIP) {
                const int kd = k / 9, kh = (k / 3) % 3, kw = k % 3;
                src = (2 - kd) * 9 + (2 - kh) * 3 + (2 - kw);
            } else {
                src = k;
            }
            const int ci = (cp0 + cp) * 2;
            const size_t wb = (size_t)(co_base + j) * Cin;
            wl2[t] = packh2(wt[(wb + ci) * 27 + src], wt[(wb + ci + 1) * 27 + src]);
        }
        __syncthreads();

        for (int cp = 0; cp < cnp; ++cp) {
            const f16* cb = in + (size_t)(cp0 + cp) * DD * HWin * 2;
            const unsigned* wc = wl2 + cp * 27 * CO_BLK;
#pragma unroll
            for (int kd = 0; kd < 3; ++kd) {
                const int di = d0 + kd - 1;
                if (di < 0 || di >= DD) continue;
#pragma unroll
                for (int kh = 0; kh < 3; ++kh) {
                    const int hi = h0 * STRIDE + kh - 1;
                    if (hi < 0 || hi >= Hin) continue;
                    const unsigned* rowu = (const unsigned*)
                        (cb + ((size_t)di * HWin + (size_t)hi * Win) * 2);
                    if (STRIDE == 1) {
                        unsigned v2[10];
                        v2[0] = (w0 > 0) ? rowu[w0 - 1] : 0u;
                        const uint4 q1 = *(const uint4*)(rowu + w0);
                        const uint4 q2 = *(const uint4*)(rowu + w0 + 4);
                        v2[1] = q1.x; v2[2] = q1.y; v2[3] = q1.z; v2[4] = q1.w;
                        v2[5] = q2.x; v2[6] = q2.y; v2[7] = q2.z; v2[8] = q2.w;
                        v2[9] = (w0 + 8 < Win) ? rowu[w0 + 8] : 0u;
                        const unsigned* wk = wc + (kd * 9 + kh * 3) * CO_BLK;
#pragma unroll
                        for (int kw = 0; kw < 3; ++kw) {
#pragma unroll
                            for (int j = 0; j < CO_BLK; ++j) {
                                const unsigned wv = wk[kw * CO_BLK + j];
#pragma unroll
                                for (int o = 0; o < 8; ++o)
                                    acc[j][o] = dot2f(v2[o + kw], wv, acc[j][o]);
                            }
                        }
                    } else {
                        unsigned v2[17];
                        const int p0 = w0 * 2;
                        v2[0] = (w0 > 0) ? rowu[p0 - 1] : 0u;
#pragma unroll
                        for (int q = 0; q < 4; ++q) {
                            const uint4 qq = *(const uint4*)(rowu + p0 + 4 * q);
                            v2[1 + 4 * q] = qq.x; v2[2 + 4 * q] = qq.y;
                            v2[3 + 4 * q] = qq.z; v2[4 + 4 * q] = qq.w;
                        }
                        const unsigned* wk = wc + (kd * 9 + kh * 3) * CO_BLK;
#pragma unroll
                        for (int kw = 0; kw < 3; ++kw) {
#pragma unroll
                            for (int j = 0; j < CO_BLK; ++j) {
                                const unsigned wv = wk[kw * CO_BLK + j];
#pragma unroll
                                for (int o = 0; o < 8; ++o)
                                    acc[j][o] = dot2f(v2[2 * o + kw], wv, acc[j][o]);
                            }
                        }
                    }
                }
            }
        }
    }

    if (OUT_IL) {
#pragma unroll
        for (int pj = 0; pj < CO_BLK / 2; ++pj) {
            f16* op = out + ((((size_t)((co_base >> 1) + pj) * DD + d0) * Hout + h0)
                             * Wout + w0) * 2;
            unsigned dw[8];
#pragma unroll
            for (int o = 0; o < 8; ++o)
                dw[o] = packh2(acc[2 * pj][o], acc[2 * pj + 1][o]);
            *(uint4*)op = make_uint4(dw[0], dw[1], dw[2], dw[3]);
            *(uint4*)(op + 8) = make_uint4(dw[4], dw[5], dw[6], dw[7]);
        }
    } else {
#pragma unroll
        for (int j = 0; j < CO_BLK; ++j) {
            f16* op = out + (((size_t)(co_base + j) * DD + d0) * Hout + h0) * Wout + w0;
            unsigned dw[4];
#pragma unroll
            for (int o = 0; o < 4; ++o)
                dw[o] = packh2(acc[j][2 * o], acc[j][2 * o + 1]);
            *(uint4*)op = make_uint4(dw[0], dw[1], dw[2], dw[3]);
        }
    }
}

// ---------------------------------------------------------------------------
// Fused conv3d( upsample2x(a + b) ), stride 1, no flip, pair-interleaved.
// ---------------------------------------------------------------------------
template<int CO_BLK>
__global__ __launch_bounds__(256, 2)
void conv3d_up_il_k(const f16* __restrict__ ia, const f16* __restrict__ ib,
                    const float* __restrict__ wt, const float* __restrict__ bias,
                    f16* __restrict__ out, int Cin, int Hlo, int Wlo)
{
    extern __shared__ unsigned wl2[];
    const int co_base = blockIdx.y * CO_BLK;

    const int Hout = 2 * Hlo, Wout = 2 * Wlo;
    const int s8 = (blockIdx.x * 256 + threadIdx.x) * 8;
    const int w0 = s8 % Wout;
    const int sh = s8 / Wout;
    const int h0 = sh % Hout;
    const int d0 = sh / Hout;
    const int lw = w0 >> 1;  // multiple of 4

    float acc[CO_BLK][8];
#pragma unroll
    for (int j = 0; j < CO_BLK; ++j) {
        const float bv = bias[co_base + j];
#pragma unroll
        for (int o = 0; o < 8; ++o) acc[j][o] = bv;
    }
    const size_t HWlo = (size_t)Hlo * Wlo;
    const int CP = Cin >> 1;

    for (int cp0 = 0; cp0 < CP; cp0 += CP_CHUNK) {
        const int cnp = (CP - cp0 < CP_CHUNK) ? (CP - cp0) : CP_CHUNK;
        __syncthreads();
        for (int t = threadIdx.x; t < cnp * 27 * CO_BLK; t += 256) {
            const int j = t % CO_BLK;
            const int k = (t / CO_BLK) % 27;
            const int cp = t / (CO_BLK * 27);
            const int ci = (cp0 + cp) * 2;
            const size_t wb = (size_t)(co_base + j) * Cin;
            wl2[t] = packh2(wt[(wb + ci) * 27 + k], wt[(wb + ci + 1) * 27 + k]);
        }
        __syncthreads();

        for (int cp = 0; cp < cnp; ++cp) {
            const f16* cba = ia + (size_t)(cp0 + cp) * DD * HWlo * 2;
            const f16* cbb = ib + (size_t)(cp0 + cp) * DD * HWlo * 2;
            const unsigned* wc = wl2 + cp * 27 * CO_BLK;
#pragma unroll
            for (int kd = 0; kd < 3; ++kd) {
                const int di = d0 + kd - 1;
                if (di < 0 || di >= DD) continue;
#pragma unroll
                for (int kh = 0; kh < 3; ++kh) {
                    const int hi = h0 + kh - 1;
                    if (hi < 0 || hi >= Hout) continue;
                    const int hlo = hi >> 1;
                    const unsigned* rua = (const unsigned*)
                        (cba + ((size_t)di * HWlo + (size_t)hlo * Wlo) * 2);
                    const unsigned* rub = (const unsigned*)
                        (cbb + ((size_t)di * HWlo + (size_t)hlo * Wlo) * 2);
                    unsigned u[6];
                    u[0] = (lw > 0) ? addh2(rua[lw - 1], rub[lw - 1]) : 0u;
                    const uint4 qa = *(const uint4*)(rua + lw);
                    const uint4 qb = *(const uint4*)(rub + lw);
                    u[1] = addh2(qa.x, qb.x); u[2] = addh2(qa.y, qb.y);
                    u[3] = addh2(qa.z, qb.z); u[4] = addh2(qa.w, qb.w);
                    u[5] = (lw + 4 < Wlo) ? addh2(rua[lw + 4], rub[lw + 4]) : 0u;
                    // upsampled window: up-w = w0-1+t, t in [0,10)
                    const unsigned v2[10] = { u[0], u[1], u[1], u[2], u[2],
                                              u[3], u[3], u[4], u[4], u[5] };
                    const unsigned* wk = wc + (kd * 9 + kh * 3) * CO_BLK;
#pragma unroll
                    for (int kw = 0; kw < 3; ++kw) {
#pragma unroll
                        for (int j = 0; j < CO_BLK; ++j) {
                            const unsigned wv = wk[kw * CO_BLK + j];
#pragma unroll
                            for (int o = 0; o < 8; ++o)
                                acc[j][o] = dot2f(v2[o + kw], wv, acc[j][o]);
                        }
                    }
                }
            }
        }
    }
#pragma unroll
    for (int pj = 0; pj < CO_BLK / 2; ++pj) {
        f16* op = out + ((((size_t)((co_base >> 1) + pj) * DD + d0) * Hout + h0)
                         * Wout + w0) * 2;
        unsigned dw[8];
#pragma unroll
        for (int o = 0; o < 8; ++o)
            dw[o] = packh2(acc[2 * pj][o], acc[2 * pj + 1][o]);
        *(uint4*)op = make_uint4(dw[0], dw[1], dw[2], dw[3]);
        *(uint4*)(op + 8) = make_uint4(dw[4], dw[5], dw[6], dw[7]);
    }
}

// ---------------------------------------------------------------------------
// fe conv: Cin=1, fp32 plain input x, interleaved f16 out (CO_BLK=4). @256^2.
// ---------------------------------------------------------------------------
__global__ __launch_bounds__(256, 2)
void conv_fe_k(const float* __restrict__ in, const float* __restrict__ wt,
               const float* __restrict__ bias, f16* __restrict__ out)
{
    __shared__ float wl[27 * 4];
    for (int t = threadIdx.x; t < 27 * 4; t += 256) {
        const int j = t % 4;
        const int k = t / 4;
        wl[t] = wt[(size_t)j * 27 + k];
    }
    __syncthreads();

    const int W = 256, H = 256;
    const int s8 = (blockIdx.x * 256 + threadIdx.x) * 8;
    const int w0 = s8 % W;
    const int sh = s8 / W;
    const int h0 = sh % H;
    const int d0 = sh / H;

    float acc[4][8];
#pragma unroll
    for (int j = 0; j < 4; ++j) {
        const float bv = bias[j];
#pragma unroll
        for (int o = 0; o < 8; ++o) acc[j][o] = bv;
    }
    const size_t HW = 65536;

#pragma unroll
    for (int kd = 0; kd < 3; ++kd) {
        const int di = d0 + kd - 1;
        if (di < 0 || di >= DD) continue;
#pragma unroll
        for (int kh = 0; kh < 3; ++kh) {
            const int hi = h0 + kh - 1;
            if (hi < 0 || hi >= H) continue;
            const float* row = in + (size_t)di * HW + (size_t)hi * W + w0;
            float v[10];
            v[0] = (w0 > 0) ? row[-1] : 0.f;
            const float4 q1 = *(const float4*)row;
            const float4 q2 = *(const float4*)(row + 4);
            v[1] = q1.x; v[2] = q1.y; v[3] = q1.z; v[4] = q1.w;
            v[5] = q2.x; v[6] = q2.y; v[7] = q2.z; v[8] = q2.w;
            v[9] = (w0 + 8 < W) ? row[8] : 0.f;
            const float* wk = wl + (kd * 9 + kh * 3) * 4;
#pragma unroll
            for (int kw = 0; kw < 3; ++kw) {
#pragma unroll
                for (int j = 0; j < 4; ++j) {
                    const float wv = wk[kw * 4 + j];
#pragma unroll
                    for (int o = 0; o < 8; ++o)
                        acc[j][o] = fmaf(v[o + kw], wv, acc[j][o]);
                }
            }
        }
    }
#pragma unroll
    for (int pj = 0; pj < 2; ++pj) {
        f16* op = out + (((size_t)pj * DD + d0) * H + h0) * (size_t)W * 2 + (size_t)w0 * 2;
        unsigned dw[8];
#pragma unroll
        for (int o = 0; o < 8; ++o)
            dw[o] = packh2(acc[2 * pj][o], acc[2 * pj + 1][o]);
        *(uint4*)op = make_uint4(dw[0], dw[1], dw[2], dw[3]);
        *(uint4*)(op + 8) = make_uint4(dw[4], dw[5], dw[6], dw[7]);
    }
}

// ---------------------------------------------------------------------------
// fo_pool over D=31. IL=true: pair-interleaved [C/2][D][HW][2]; else plain
// [C][D][HW]. z/f/a1 share the layout; a2 (x, fp32) plain-only.
// out = h_d + a1? + a2?
// ---------------------------------------------------------------------------
template<bool IL, typename TA1, typename TA2, typename TO>
__global__ __launch_bounds__(256)
void fo_pool_k(const f16* __restrict__ z, const f16* __restrict__ f,
               TO* __restrict__ out, const TA1* __restrict__ a1,
               const TA2* __restrict__ a2, int C, int HW, int reverse)
{
    const long long idx = (long long)blockIdx.x * 256 + threadIdx.x;
    if (idx >= (long long)C * HW) return;
    size_t base; size_t step;
    if (IL) {
        const long long pairIdx = idx / (2LL * HW);
        const int rem = (int)(idx - pairIdx * 2LL * HW);
        const int p = rem >> 1;
        const int par = rem & 1;
        base = ((size_t)pairIdx * DD * HW + p) * 2 + par;
        step = (size_t)HW * 2;
    } else {
        const int c = (int)(idx / HW);
        const int p = (int)(idx - (long long)c * HW);
        base = (size_t)c * DD * HW + p;
        step = (size_t)HW;
    }
    float h = 0.f;
    if (!reverse) {
        for (int d = 0; d < DD; ++d) {
            const size_t off = base + (size_t)d * step;
            const float zz = tanhf(toF(z[off]));
            const float ff = sigm(toF(f[off]));
            h = ff * h + (1.f - ff) * zz;
            float v = h;
            if (a1) v += toF(a1[off]);
            if (a2) v += toF(a2[off]);
            stv(out + off, v);
        }
    } else {
        for (int d = DD - 1; d >= 0; --d) {
            const size_t off = base + (size_t)d * step;
            const float zz = tanhf(toF(z[off]));
            const float ff = sigm(toF(f[off]));
            h = ff * h + (1.f - ff) * zz;
            float v = h;
            if (a1) v += toF(a1[off]);
            if (a2) v += toF(a2[off]);
            stv(out + off, v);
        }
    }
}

// Diagnostic: encode ws_size (MB) into output if workspace too small.
__global__ __launch_bounds__(256)
void diag_k(float* out, float v, int n)
{
    const int i = blockIdx.x * 256 + threadIdx.x;
    if (i < n) out[i] = v;
}

// ---------------------------------------------------------------------------

static inline void conv_launch(const f16* in, const float* w, const float* b,
                               f16* out, int Cin, int co0, int nCo,
                               int Hin, int Win, int Hout, int Wout,
                               int stride, bool flip, hipStream_t s)
{
    const unsigned gx = (unsigned)((DD * (long long)Hout * Wout) / 2048);
    const float* wp = w + (size_t)co0 * Cin * 27;
    const float* bp = b + co0;
    const int cpc = (Cin / 2 < CP_CHUNK) ? Cin / 2 : CP_CHUNK;
    if (stride == 2) {
        dim3 grid(gx, nCo / 8);
        conv3d_il_k<2, false, 8, true><<<grid, 256, (size_t)cpc * 27 * 8 * 4, s>>>(
            in, wp, bp, out, Cin, Hin, Win, Hout, Wout);
    } else if (flip) {
        if (nCo % 8 == 0) {
            dim3 grid(gx, nCo / 8);
            conv3d_il_k<1, true, 8, true><<<grid, 256, (size_t)cpc * 27 * 8 * 4, s>>>(
                in, wp, bp, out, Cin, Hin, Win, Hout, Wout);
        } else if (nCo % 4 == 0) {
            dim3 grid(gx, nCo / 4);
            conv3d_il_k<1, true, 4, true><<<grid, 256, (size_t)cpc * 27 * 4 * 4, s>>>(
                in, wp, bp, out, Cin, Hin, Win, Hout, Wout);
        } else {  // rec layer: nCo == 3, plain output
            dim3 grid(gx, 1);
            conv3d_il_k<1, true, 3, false><<<grid, 256, (size_t)cpc * 27 * 3 * 4, s>>>(
                in, wp, bp, out, Cin, Hin, Win, Hout, Wout);
        }
    } else {
        if (nCo % 8 == 0) {
            dim3 grid(gx, nCo / 8);
            conv3d_il_k<1, false, 8, true><<<grid, 256, (size_t)cpc * 27 * 8 * 4, s>>>(
                in, wp, bp, out, Cin, Hin, Win, Hout, Wout);
        } else {
            dim3 grid(gx, nCo / 4);
            conv3d_il_k<1, false, 4, true><<<grid, 256, (size_t)cpc * 27 * 4 * 4, s>>>(
                in, wp, bp, out, Cin, Hin, Win, Hout, Wout);
        }
    }
}

static inline void conv_up_launch(const f16* ia, const f16* ib, const float* w,
                                  const float* b, f16* out, int Cin, int co0,
                                  int nCo, int Hlo, int Wlo, hipStream_t s)
{
    const unsigned gx = (unsigned)((DD * 4LL * Hlo * Wlo) / 2048);
    const int cpc = (Cin / 2 < CP_CHUNK) ? Cin / 2 : CP_CHUNK;
    if (nCo % 8 == 0) {
        dim3 grid(gx, nCo / 8);
        conv3d_up_il_k<8><<<grid, 256, (size_t)cpc * 27 * 8 * 4, s>>>(
            ia, ib, w + (size_t)co0 * Cin * 27, b + co0, out, Cin, Hlo, Wlo);
    } else {
        dim3 grid(gx, nCo / 4);
        conv3d_up_il_k<4><<<grid, 256, (size_t)cpc * 27 * 4 * 4, s>>>(
            ia, ib, w + (size_t)co0 * Cin * 27, b + co0, out, Cin, Hlo, Wlo);
    }
}

template<bool IL, typename TA1, typename TA2, typename TO>
static inline void pool_launch(const f16* z, const f16* f, TO* o, const TA1* a1,
                               const TA2* a2, int C, int HW, int rev,
                               hipStream_t s)
{
    const long long tot = (long long)C * HW;
    fo_pool_k<IL, TA1, TA2, TO><<<(unsigned)((tot + 255) / 256), 256, 0, s>>>(
        z, f, o, a1, a2, C, HW, rev);
}

// ---------------------------------------------------------------------------
// Memory plan (units of U). Pool = 56 U f16. Same slot plan as rounds 6-10;
// all base shifts are whole channel-pairs, so interleaving is transparent.
// ---------------------------------------------------------------------------
static void run_net(const float* x, const float* const* W, const float* const* B,
                    float* out, f16* P, hipStream_t s)
{
    const f16* np = nullptr;
    const float* npf = nullptr;

    fill_k<<<2048, 256, 0, s>>>(P, POOL_UNITS * U);

    f16* FE = P + 32 * U;
    // ---- fe = biqrnn(conv(x)) : 1 -> 48 gates -> 16 ch @256, chunks of 4 ---
    for (int a = 0; a < 16; a += 4) {
        conv_fe_k<<<992, 256, 0, s>>>(x, W[0] + (size_t)a * 27,        B[0] + a,      P);
        conv_fe_k<<<992, 256, 0, s>>>(x, W[0] + (size_t)(16 + a) * 27, B[0] + 16 + a, P + 4 * U);
        conv_fe_k<<<992, 256, 0, s>>>(x, W[0] + (size_t)(32 + a) * 27, B[0] + 32 + a, P + 8 * U);
        pool_launch<true, f16, float, f16>(P, P + 4 * U, P + 12 * U, np, npf, 4, 65536, 0, s);
        pool_launch<true, f16, float, f16>(P, P + 8 * U, FE + (size_t)a * U, P + 12 * U, npf, 4, 65536, 1, s);
    }

    // ---- e0 = qrnn(conv(fe), fwd) : 16 -> 32 -> 16 @256, chunks of 8 -------
    f16* E0 = P + 16 * U;
    for (int a = 0; a < 16; a += 8) {
        conv_launch(FE, W[1], B[1], P,         16, a,      8, 256, 256, 256, 256, 1, false, s);
        conv_launch(FE, W[1], B[1], P + 8 * U, 16, 16 + a, 8, 256, 256, 256, 256, 1, false, s);
        pool_launch<true, f16, float, f16>(P, P + 8 * U, E0 + (size_t)a * U, np, npf, 8, 65536, 0, s);
    }
    // FE dead (recomputed later).

    // ---- e1 = qrnn(conv(e0, s2), rev) : 16 -> 64 -> 32 @128 ----------------
    f16* E1 = P;
    {
        f16* G = P + 32 * U;
        conv_launch(E0, W[2], B[2], G, 16, 0, 64, 256, 256, 128, 128, 2, false, s);
        pool_launch<true, f16, float, f16>(G, G + 8 * U, E1, np, npf, 32, 16384, 1, s);
    }

    // ---- e2 = qrnn(conv(e1), fwd) : 32 -> 64 -> 32 @128 --------------------
    f16* E2 = P + 8 * U;
    {
        f16* G = P + 32 * U;
        conv_launch(E1, W[3], B[3], G, 32, 0, 64, 128, 128, 128, 128, 1, false, s);
        pool_launch<true, f16, float, f16>(G, G + 8 * U, E2, np, npf, 32, 16384, 0, s);
    }

    // ---- e3 = qrnn(conv(e2, s2), rev) : 32 -> 128 -> 64 @64 ----------------
    f16* E3 = P + 32 * U;
    {
        f16* G = P + 48 * U;
        conv_launch(E2, W[4], B[4], G, 32, 0, 128, 128, 128, 64, 64, 2, false, s);
        pool_launch<true, f16, float, f16>(G, G + 4 * U, E3, np, npf, 64, 4096, 1, s);
    }

    // ---- e4 = qrnn(conv(e3), fwd) : 64 -> 128 -> 64 @64 --------------------
    f16* E4 = P + 40 * U;
    {
        f16* G = P + 48 * U;
        conv_launch(E3, W[5], B[5], G, 64, 0, 128, 64, 64, 64, 64, 1, false, s);
        pool_launch<true, f16, float, f16>(G, G + 4 * U, E4, np, npf, 64, 4096, 0, s);
    }

    // ---- d0 = qrnn(deconv(e4), rev) : 64 -> 128 -> 64 @64 ------------------
    f16* D0 = P + 44 * U;
    {
        f16* G = P + 48 * U;
        conv_launch(E4, W[6], B[6], G, 64, 0, 128, 64, 64, 64, 64, 1, true, s);
        pool_launch<true, f16, float, f16>(G, G + 4 * U, D0, np, npf, 64, 4096, 1, s);
    }
    // E4 dead.

    // ---- d1 = qrnn(conv(up(d0+e3)), fwd) + e2 : 64 -> 64 -> 32 @128 --------
    f16* D1 = P + 36 * U;
    for (int a = 0; a < 32; a += 16) {
        f16* G = P + 48 * U;  // z 16ch@V2 = 4U, f 4U
        conv_up_launch(D0, E3, W[7], B[7], G,         64, a,      16, 64, 64, s);
        conv_up_launch(D0, E3, W[7], B[7], G + 4 * U, 64, 32 + a, 16, 64, 64, s);
        pool_launch<true, f16, float, f16>(G, G + 4 * U, D1 + (size_t)a * V2,
                                           E2 + (size_t)a * V2, npf, 16, 16384, 0, s);
    }
    // E2, E3, D0 dead.

    // ---- d2 = qrnn(deconv(d1), rev) : 32 -> 64 -> 32 @128 ------------------
    f16* D2 = P + 8 * U;  // over dead E2
    for (int a = 0; a < 32; a += 16) {
        f16* G = P + 48 * U;
        conv_launch(D1, W[8], B[8], G,         32, a,      16, 128, 128, 128, 128, 1, true, s);
        conv_launch(D1, W[8], B[8], G + 4 * U, 32, 32 + a, 16, 128, 128, 128, 128, 1, true, s);
        pool_launch<true, f16, float, f16>(G, G + 4 * U, D2 + (size_t)a * V2, np, npf, 16, 16384, 1, s);
    }
    // D1 dead.

    // ---- d3 = qrnn(conv(up(d2+e1)), fwd) + e0 : 32 -> 32 -> 16 @256 --------
    f16* D3 = P + 32 * U;  // fresh 16U
    for (int a = 0; a < 16; a += 4) {
        f16* G = P + 48 * U;  // z 4ch@U=4U, f 4U
        conv_up_launch(D2, E1, W[9], B[9], G,         32, a,      4, 128, 128, s);
        conv_up_launch(D2, E1, W[9], B[9], G + 4 * U, 32, 16 + a, 4, 128, 128, s);
        pool_launch<true, f16, float, f16>(G, G + 4 * U, D3 + (size_t)a * U,
                                           E0 + (size_t)a * U, npf, 4, 65536, 0, s);
    }
    // E0, E1, D2 dead.

    // ---- recompute fe -> FE2 = [0,16), gates at [16,32) --------------------
    f16* FE2 = P;
    for (int a = 0; a < 16; a += 4) {
        f16* G = P + 16 * U;
        conv_fe_k<<<992, 256, 0, s>>>(x, W[0] + (size_t)a * 27,        B[0] + a,      G);
        conv_fe_k<<<992, 256, 0, s>>>(x, W[0] + (size_t)(16 + a) * 27, B[0] + 16 + a, G + 4 * U);
        conv_fe_k<<<992, 256, 0, s>>>(x, W[0] + (size_t)(32 + a) * 27, B[0] + 32 + a, G + 8 * U);
        pool_launch<true, f16, float, f16>(G, G + 4 * U, G + 12 * U, np, npf, 4, 65536, 0, s);
        pool_launch<true, f16, float, f16>(G, G + 8 * U, FE2 + (size_t)a * U, G + 12 * U, npf, 4, 65536, 1, s);
    }

    // ---- d4 = qrnn(deconv(d3), rev) + fe : 16 -> 32 -> 16 @256 -------------
    f16* D4 = P + 16 * U;
    for (int a = 0; a < 16; a += 4) {
        f16* G = P + 48 * U;
        conv_launch(D3, W[10], B[10], G,         16, a,      4, 256, 256, 256, 256, 1, true, s);
        conv_launch(D3, W[10], B[10], G + 4 * U, 16, 16 + a, 4, 256, 256, 256, 256, 1, true, s);
        pool_launch<true, f16, float, f16>(G, G + 4 * U, D4 + (size_t)a * U,
                                           FE2 + (size_t)a * U, npf, 4, 65536, 1, s);
    }
    // D3, FE2 dead.

    // ---- out = biqrnn(deconv(d4)) + x : 16 -> 3 -> 1 @256 -> fp32 d_out ----
    {
        f16* G = P + 32 * U;   // plain: ch0 z, ch1 f1, ch2 f2
        f16* TMP = P + 35 * U;
        conv_launch(D4, W[11], B[11], G, 16, 0, 3, 256, 256, 256, 256, 1, true, s);
        pool_launch<false, f16, float, f16>(G, G + 1 * U, TMP, np, npf, 1, 65536, 0, s);
        pool_launch<false, f16, float, float>(G, G + 2 * U, out, TMP, x, 1, 65536, 1, s);
    }
}

extern "C" void kernel_launch(void* const* d_in, const int* in_sizes, int n_in,
                              void* d_out, int out_size, void* d_ws, size_t ws_size,
                              hipStream_t stream)
{
    const float* x = (const float*)d_in[0];
    const float* W[12];
    const float* B[12];
    for (int i = 0; i < 12; ++i) {
        W[i] = (const float*)d_in[1 + 2 * i];
        B[i] = (const float*)d_in[2 + 2 * i];
    }

    const size_t need = (size_t)(POOL_UNITS * U) * sizeof(f16);  // ~227 MB
    if (ws_size >= need) {
        run_net(x, W, B, (float*)d_out, (f16*)d_ws, stream);
    } else {
        const float ws_mb = (float)((double)ws_size / 1048576.0);
        diag_k<<<(out_size + 255) / 256, 256, 0, stream>>>(
            (float*)d_out, ws_mb, out_size);
    }
}